// Round 7
// baseline (921.959 us; speedup 1.0000x reference)
//
#include <hip/hip_runtime.h>
#include <hip/hip_bf16.h>
#include <stdint.h>

// GCN: per layer  X_agg = (A_sym + D^-1) X ;  Y = X_agg @ W ; BN(gamma,beta) ; relu
// bias b cancels through BN -> skipped. agg-before-GEMM is exact-math equivalent.
// DETERMINISM (bitwise): CSR rows canonically sorted (k_sort) so the f32 gather sums
// in a fixed order; BN stats via fixed-order shfl + per-block partials + fixed-order
// finalize (NO float atomics anywhere).
// X row-major bf16 [MPAD][K]; Y bf16; BN stats fused into GEMM epilogue.

#define NN 100000
#define EE 1600000
#define BB 64
#define MPAD 100096   // 391*256, zero-padded rows
#define NBM (MPAD / 256)   // 391 gemm row-blocks

typedef __attribute__((ext_vector_type(8))) short short8;
typedef __attribute__((ext_vector_type(4))) float f32x4;

__device__ __forceinline__ float bflo(uint32_t v){ return __uint_as_float(v << 16); }
__device__ __forceinline__ float bfhi(uint32_t v){ return __uint_as_float(v & 0xffff0000u); }
__device__ __forceinline__ uint32_t bfrne(float x){
  uint32_t u = __float_as_uint(x);
  return (u + 0x7fffu + ((u >> 16) & 1u)) >> 16;
}
__device__ __forceinline__ uint32_t bfpack(float a, float b){ return bfrne(a) | (bfrne(b) << 16); }
__device__ __forceinline__ float phi(long long p){
  return __uint_as_float((uint32_t)((unsigned long long)p >> 32));
}

__device__ __forceinline__ void gload_lds16(const void* g, void* l){
  __builtin_amdgcn_global_load_lds(
      (const __attribute__((address_space(1))) uint32_t*)g,
      (__attribute__((address_space(3))) uint32_t*)l, 16, 0, 0);
}

// ---------------- setup: degree, rsqrt, CSR ----------------
__global__ void k_deg(const int* __restrict__ dst, int* __restrict__ degi){
  for (int e = blockIdx.x * blockDim.x + threadIdx.x; e < EE; e += gridDim.x * blockDim.x)
    atomicAdd(&degi[dst[e]], 1);
}

__global__ void k_scan1(const int* __restrict__ degi, int* __restrict__ rp, int* __restrict__ bsum,
                        float* __restrict__ dis){
  __shared__ int lds[256];
  int b = blockIdx.x, t = threadIdx.x;
  int base = b * 1024 + t * 4;
  int v0 = (base + 0 < NN) ? degi[base + 0] : 0;
  int v1 = (base + 1 < NN) ? degi[base + 1] : 0;
  int v2 = (base + 2 < NN) ? degi[base + 2] : 0;
  int v3 = (base + 3 < NN) ? degi[base + 3] : 0;
  if (base + 0 < NN) dis[base + 0] = rsqrtf((float)v0 + 1.0f);
  if (base + 1 < NN) dis[base + 1] = rsqrtf((float)v1 + 1.0f);
  if (base + 2 < NN) dis[base + 2] = rsqrtf((float)v2 + 1.0f);
  if (base + 3 < NN) dis[base + 3] = rsqrtf((float)v3 + 1.0f);
  int s = v0 + v1 + v2 + v3;
  lds[t] = s; __syncthreads();
  for (int off = 1; off < 256; off <<= 1){
    int x = (t >= off) ? lds[t - off] : 0; __syncthreads();
    lds[t] += x; __syncthreads();
  }
  int excl = lds[t] - s;
  if (t == 255) bsum[b] = lds[255];
  if (base + 0 < NN) rp[base + 0] = excl;
  if (base + 1 < NN) rp[base + 1] = excl + v0;
  if (base + 2 < NN) rp[base + 2] = excl + v0 + v1;
  if (base + 3 < NN) rp[base + 3] = excl + v0 + v1 + v2;
}

__global__ void k_scan2(int* __restrict__ bsum, int nb){
  if (blockIdx.x == 0 && threadIdx.x == 0){
    int run = 0;
    for (int i = 0; i < nb; ++i){ int t = bsum[i]; bsum[i] = run; run += t; }
  }
}

__global__ void k_scan3(int* __restrict__ rp, int* __restrict__ cursor, const int* __restrict__ bsum){
  int b = blockIdx.x, t = threadIdx.x;
  int add = bsum[b];
  int base = b * 1024 + t * 4;
  #pragma unroll
  for (int j = 0; j < 4; ++j){
    int i = base + j;
    if (i < NN){ int v = rp[i] + add; rp[i] = v; cursor[i] = v; }
  }
  if (b == 0 && t == 0) rp[NN] = EE;
}

__global__ void k_fill(const int* __restrict__ src, const int* __restrict__ dst,
                       const float* __restrict__ dis, int* __restrict__ cursor,
                       long long* __restrict__ cp){
  for (int e = blockIdx.x * blockDim.x + threadIdx.x; e < EE; e += gridDim.x * blockDim.x){
    int s = src[e], d = dst[e];
    int pos = atomicAdd(&cursor[d], 1);
    float nrm = dis[s] * dis[d];
    long long v = (long long)(unsigned int)s | ((long long)(unsigned int)__float_as_uint(nrm) << 32);
    cp[pos] = v;
  }
}

// canonical per-row order -> the entire pipeline becomes bitwise deterministic.
// (slot order from k_fill's atomics is the only nondeterminism; sort removes it.
//  duplicate (src,dst) edges pack identical 64-bit values -> order irrelevant.)
__global__ void k_sort(const int* __restrict__ rp, long long* __restrict__ cp){
  int row = blockIdx.x * 256 + threadIdx.x;
  if (row >= NN) return;
  int beg = rp[row], end = rp[row + 1];
  for (int i = beg + 1; i < end; ++i){
    long long key = cp[i];
    int j = i - 1;
    while (j >= beg && cp[j] > key){ cp[j + 1] = cp[j]; --j; }
    cp[j + 1] = key;
  }
}

// ---------------- all weights -> bf16 transposed Wt[c][k] ----------------
__global__ void k_wtall(const float* __restrict__ W0, const float* __restrict__ Wr,
                        uint16_t* __restrict__ Wt0, uint16_t* __restrict__ Wt1,
                        uint16_t* __restrict__ Wt2){
  int i = blockIdx.x * 256 + threadIdx.x;
  if (i < 32768){
    int c = i >> 7, k = i & 127;
    Wt0[i] = (uint16_t)bfrne(W0[k * 256 + c]);
  } else if (i < 32768 + 131072){
    int j = i - 32768;
    int m = j >> 16, jj = j & 65535;
    int c = jj >> 8, k = jj & 255;
    uint16_t v = (uint16_t)bfrne(Wr[m * 65536 + k * 256 + c]);
    if (m == 0) Wt1[jj] = v; else Wt2[jj] = v;
  }
}

// ---------------- x (f32) -> bf16 row-major [MPAD][128], zero-pad rows ----------------
__global__ void k_cvtx(const float* __restrict__ x, uint32_t* __restrict__ Xb){
  int i = blockIdx.x * 256 + threadIdx.x;   // over MPAD*64
  if (i >= MPAD * 64) return;
  int row = i >> 6;
  uint32_t r = 0u;
  if (row < NN){
    int col = (i & 63) * 2;
    r = bfpack(x[row * 128 + col], x[row * 128 + col + 1]);
  }
  Xb[i] = r;
}

// ---------------- aggregation K=256: one wave per row, uint2 per lane ----------------
__global__ void k_agg256(const uint2* __restrict__ Xin, const int* __restrict__ rp,
                         const long long* __restrict__ cp, const float* __restrict__ dis,
                         uint2* __restrict__ Xout){
  int lane = threadIdx.x & 63;
  int slot = threadIdx.x >> 6;
  int row0 = blockIdx.x * 16 + slot;
  for (int rr = 0; rr < 4; ++rr){
    int row = row0 + rr * 4;
    if (row >= NN){
      if (row < MPAD){ uint2 z = {0u, 0u}; Xout[(size_t)row * 64 + lane] = z; }
      continue;
    }
    int beg = rp[row], end = rp[row + 1];
    float a0 = 0.f, a1 = 0.f, a2 = 0.f, a3 = 0.f;
    int e = beg;
    for (; e + 8 <= end; e += 8){
      long long p[8]; uint2 v[8];
      #pragma unroll
      for (int u = 0; u < 8; ++u) p[u] = cp[e + u];
      #pragma unroll
      for (int u = 0; u < 8; ++u) v[u] = Xin[(size_t)(int)p[u] * 64 + lane];
      #pragma unroll
      for (int u = 0; u < 8; ++u){
        float w = phi(p[u]);
        a0 += w * bflo(v[u].x); a1 += w * bfhi(v[u].x);
        a2 += w * bflo(v[u].y); a3 += w * bfhi(v[u].y);
      }
    }
    for (; e < end; ++e){
      long long p0 = cp[e];
      float w = phi(p0);
      uint2 v = Xin[(size_t)(int)p0 * 64 + lane];
      a0 += w * bflo(v.x); a1 += w * bfhi(v.x);
      a2 += w * bflo(v.y); a3 += w * bfhi(v.y);
    }
    float dv = dis[row]; float sn = dv * dv;
    uint2 vs = Xin[(size_t)row * 64 + lane];
    a0 += sn * bflo(vs.x); a1 += sn * bfhi(vs.x);
    a2 += sn * bflo(vs.y); a3 += sn * bfhi(vs.y);
    uint2 o; o.x = bfpack(a0, a1); o.y = bfpack(a2, a3);
    Xout[(size_t)row * 64 + lane] = o;
  }
}

// ---------------- aggregation K=128: half-wave pair, uint2 per lane ----------------
__global__ void k_agg128(const uint2* __restrict__ Xin, const int* __restrict__ rp,
                         const long long* __restrict__ cp, const float* __restrict__ dis,
                         uint2* __restrict__ Xout){
  int lane = threadIdx.x & 63;
  int half = lane >> 5, j = lane & 31;
  int slot = threadIdx.x >> 6;
  int row0 = blockIdx.x * 16 + slot;
  for (int rr = 0; rr < 4; ++rr){
    int row = row0 + rr * 4;
    if (row >= NN){
      if (row < MPAD && half == 0){ uint2 z = {0u, 0u}; Xout[(size_t)row * 32 + j] = z; }
      continue;
    }
    int beg = rp[row], end = rp[row + 1];
    float a0 = 0.f, a1 = 0.f, a2 = 0.f, a3 = 0.f;
    int e = beg;
    for (; e + 8 <= end; e += 8){
      long long p[4]; uint2 v[4];
      #pragma unroll
      for (int u = 0; u < 4; ++u) p[u] = cp[e + u * 2 + half];
      #pragma unroll
      for (int u = 0; u < 4; ++u) v[u] = Xin[(size_t)(int)p[u] * 32 + j];
      #pragma unroll
      for (int u = 0; u < 4; ++u){
        float w = phi(p[u]);
        a0 += w * bflo(v[u].x); a1 += w * bfhi(v[u].x);
        a2 += w * bflo(v[u].y); a3 += w * bfhi(v[u].y);
      }
    }
    for (; e < end; e += 2){
      int idx = e + half;
      bool ok = idx < end;
      long long p0 = cp[ok ? idx : end - 1];
      float w = ok ? phi(p0) : 0.f;
      uint2 v = Xin[(size_t)(int)p0 * 32 + j];
      a0 += w * bflo(v.x); a1 += w * bfhi(v.x);
      a2 += w * bflo(v.y); a3 += w * bfhi(v.y);
    }
    a0 += __shfl_xor(a0, 32); a1 += __shfl_xor(a1, 32);
    a2 += __shfl_xor(a2, 32); a3 += __shfl_xor(a3, 32);
    if (half == 0){
      float dv = dis[row]; float sn = dv * dv;
      uint2 vs = Xin[(size_t)row * 32 + j];
      a0 += sn * bflo(vs.x); a1 += sn * bfhi(vs.x);
      a2 += sn * bflo(vs.y); a3 += sn * bfhi(vs.y);
      uint2 o; o.x = bfpack(a0, a1); o.y = bfpack(a2, a3);
      Xout[(size_t)row * 32 + j] = o;
    }
  }
}

// ---------------- GEMM: Y[MPAD][256](bf16) = A[MPAD][K] * Wt[256][K]^T, fused BN stats ----------------
// 256x128 tile, 512 threads (8 waves, 4x2), double-buffered global_load_lds staging.
// Stats: fixed-order wave shfl -> per-wave LDS partials -> fixed-order combine -> pstat (no atomics).
template<int K>
__global__ __launch_bounds__(512) void k_gemm(const uint16_t* __restrict__ A,
                                              const uint16_t* __restrict__ Bt,
                                              uint32_t* __restrict__ Cb,
                                              float* __restrict__ pstat){
  __shared__ __align__(16) uint16_t lA[2][8192];   // chunk c = k8*256 + r
  __shared__ __align__(16) uint16_t lB[2][4096];   // chunk c = k8*128 + r
  __shared__ float lp[8][128];                      // [wave][64 colsum | 64 colsumsq]
  int tid = threadIdx.x;
  int l = tid & 63;
  int bm = blockIdx.x, bn = blockIdx.y;

  f32x4 acc[4][4];
  #pragma unroll
  for (int m = 0; m < 4; ++m)
    #pragma unroll
    for (int n = 0; n < 4; ++n){ f32x4 z = {0.f,0.f,0.f,0.f}; acc[m][n] = z; }

  int w = tid >> 6, wr = w >> 1, wc = w & 1;
  int rbase = wr * 64, cbase = wc * 64;
  int lrow = l & 15, lk8 = l >> 4;

  auto stage = [&](int kt, int buf){
    #pragma unroll
    for (int i = 0; i < 2; ++i){
      int c = i * 512 + tid;
      int k8 = c >> 8, r = c & 255;
      size_t ga = (size_t)(bm * 256 + r) * K + kt * 32 + k8 * 8;
      gload_lds16((const char*)(A + ga), (char*)&lA[buf][c * 8]);
    }
    int k8b = tid >> 7, rb = tid & 127;
    size_t gb = (size_t)(bn * 128 + rb) * K + kt * 32 + k8b * 8;
    gload_lds16((const char*)(Bt + gb), (char*)&lB[buf][tid * 8]);
  };

  stage(0, 0);
  __syncthreads();
  constexpr int NT = K / 32;
  for (int kt = 0; kt < NT; ++kt){
    int cur = kt & 1;
    if (kt + 1 < NT) stage(kt + 1, cur ^ 1);
    short8 afr[4], bfr[4];
    #pragma unroll
    for (int m = 0; m < 4; ++m)
      afr[m] = *(const short8*)&lA[cur][(lk8 * 256 + rbase + m * 16 + lrow) * 8];
    #pragma unroll
    for (int n = 0; n < 4; ++n)
      bfr[n] = *(const short8*)&lB[cur][(lk8 * 128 + cbase + n * 16 + lrow) * 8];
    #pragma unroll
    for (int m = 0; m < 4; ++m)
      #pragma unroll
      for (int n = 0; n < 4; ++n)
        acc[m][n] = __builtin_amdgcn_mfma_f32_16x16x32_bf16(afr[m], bfr[n], acc[m][n], 0, 0, 0);
    __syncthreads();
  }

  // C write bf16 (C/D: col = lane&15, row = (lane>>4)*4 + reg) + column partials
  int grow0 = bm * 256 + rbase + (l >> 4) * 4;
  int gcol0 = bn * 128 + cbase + (l & 15);
  uint16_t* C16 = (uint16_t*)Cb;
  float sa[4] = {0.f,0.f,0.f,0.f}, sb[4] = {0.f,0.f,0.f,0.f};
  #pragma unroll
  for (int m = 0; m < 4; ++m){
    #pragma unroll
    for (int n = 0; n < 4; ++n){
      int col = gcol0 + n * 16;
      int r0 = grow0 + m * 16;
      f32x4 v = acc[m][n];
      #pragma unroll
      for (int q = 0; q < 4; ++q){
        C16[(size_t)(r0 + q) * 256 + col] = (uint16_t)bfrne(v[q]);
        sa[n] += v[q]; sb[n] += v[q] * v[q];
      }
    }
  }
  #pragma unroll
  for (int n = 0; n < 4; ++n){
    sa[n] += __shfl_xor(sa[n], 16); sa[n] += __shfl_xor(sa[n], 32);
    sb[n] += __shfl_xor(sb[n], 16); sb[n] += __shfl_xor(sb[n], 32);
  }
  if (l < 16){
    #pragma unroll
    for (int n = 0; n < 4; ++n){
      lp[w][n * 16 + l] = sa[n];
      lp[w][64 + n * 16 + l] = sb[n];
    }
  }
  __syncthreads();
  if (tid < 256){
    int kind = tid >> 7, c = tid & 127;    // c = column within this 128-col tile
    int wc2 = c >> 6, cc = c & 63;
    float v = lp[wc2][kind * 64 + cc] + lp[2 + wc2][kind * 64 + cc]
            + lp[4 + wc2][kind * 64 + cc] + lp[6 + wc2][kind * 64 + cc];
    pstat[(size_t)(bm * 2 + bn) * 256 + kind * 128 + c] = v;
  }
}

// finalize: fixed-order sum of per-block partials (f64) -> scale/shift. Deterministic.
__global__ void k_finalize(const float* __restrict__ pstat, const float* __restrict__ gamma,
                           const float* __restrict__ beta, float* __restrict__ ss){
  int c = threadIdx.x;            // global column 0..255
  int bn = c >> 7, lc = c & 127;
  double s = 0., s2 = 0.;
  for (int bm = 0; bm < NBM; ++bm){
    const float* p = pstat + (size_t)(bm * 2 + bn) * 256;
    s  += (double)p[lc];
    s2 += (double)p[128 + lc];
  }
  double mean = s / (double)NN;
  double var  = s2 / (double)NN - mean * mean;
  float rstd = rsqrtf((float)var + 1e-5f);
  float sc = gamma[c] * rstd;
  ss[c] = sc;
  ss[256 + c] = beta[c] - (float)mean * sc;
}

// ---------------- BN + relu on bf16 Y -> bf16 X row-major [MPAD][256] ----------------
__global__ void k_bnapply(const uint4* __restrict__ Y, const float* __restrict__ ss,
                          uint4* __restrict__ X){
  int i = blockIdx.x * 256 + threadIdx.x;    // over MPAD*32, 8 bf16 each
  if (i >= MPAD * 32) return;
  uint4 v = Y[i];
  int c0 = (i & 31) * 8;
  float r0 = fmaxf(bflo(v.x) * ss[c0 + 0] + ss[256 + c0 + 0], 0.f);
  float r1 = fmaxf(bfhi(v.x) * ss[c0 + 1] + ss[256 + c0 + 1], 0.f);
  float r2 = fmaxf(bflo(v.y) * ss[c0 + 2] + ss[256 + c0 + 2], 0.f);
  float r3 = fmaxf(bfhi(v.y) * ss[c0 + 3] + ss[256 + c0 + 3], 0.f);
  float r4 = fmaxf(bflo(v.z) * ss[c0 + 4] + ss[256 + c0 + 4], 0.f);
  float r5 = fmaxf(bfhi(v.z) * ss[c0 + 5] + ss[256 + c0 + 5], 0.f);
  float r6 = fmaxf(bflo(v.w) * ss[c0 + 6] + ss[256 + c0 + 6], 0.f);
  float r7 = fmaxf(bfhi(v.w) * ss[c0 + 7] + ss[256 + c0 + 7], 0.f);
  uint4 o;
  o.x = bfpack(r0, r1); o.y = bfpack(r2, r3);
  o.z = bfpack(r4, r5); o.w = bfpack(r6, r7);
  X[i] = o;
}

// ---------------- segment starts + pooling (8-way row split) ----------------
__global__ void k_segstart(const int* __restrict__ batch, int* __restrict__ seg){
  int g = threadIdx.x;
  if (g > BB) return;
  if (g == BB){ seg[BB] = NN; return; }
  int lo = 0, hi = NN;
  while (lo < hi){ int mid = (lo + hi) >> 1; if (batch[mid] < g) lo = mid + 1; else hi = mid; }
  seg[g] = lo;
}

__global__ void k_poolpart(const uint32_t* __restrict__ X, const int* __restrict__ seg,
                           float* __restrict__ pb){
  int g = blockIdx.x, c = blockIdx.y, t = threadIdx.x;   // 128 threads
  int s = seg[g], e = seg[g + 1];
  int len = e - s;
  int c0 = s + (int)(((long long)len * c) >> 3);
  int c1 = s + (int)(((long long)len * (c + 1)) >> 3);
  float sm0 = 0.f, sm1 = 0.f, mx0 = -1e30f, mx1 = -1e30f;
  #pragma unroll 4
  for (int r = c0; r < c1; ++r){
    uint32_t v = X[(size_t)r * 128 + t];
    float a = bflo(v), b2 = bfhi(v);
    sm0 += a; sm1 += b2;
    mx0 = fmaxf(mx0, a); mx1 = fmaxf(mx1, b2);
  }
  float* p = pb + (size_t)(g * 8 + c) * 512;
  p[2 * t] = sm0; p[2 * t + 1] = sm1;
  p[256 + 2 * t] = mx0; p[256 + 2 * t + 1] = mx1;
}

__global__ void k_poolred(const float* __restrict__ pb, const int* __restrict__ seg,
                          float* __restrict__ out){
  int g = blockIdx.x, cc = threadIdx.x;   // 256 threads
  float s = 0.f, m = -1e30f;
  #pragma unroll
  for (int c = 0; c < 8; ++c){
    const float* p = pb + (size_t)(g * 8 + c) * 512;
    s += p[cc];
    m = fmaxf(m, p[256 + cc]);
  }
  float inv = 1.0f / (float)(seg[g + 1] - seg[g]);
  out[g * 512 + cc] = s * inv;
  out[g * 512 + 256 + cc] = m;
}

// ---------------- launch ----------------
extern "C" void kernel_launch(void* const* d_in, const int* in_sizes, int n_in,
                              void* d_out, int out_size, void* d_ws, size_t ws_size,
                              hipStream_t stream){
  const float* x     = (const float*)d_in[0];
  const float* W0    = (const float*)d_in[1];
  const float* Wr    = (const float*)d_in[2];
  const float* gamma = (const float*)d_in[4];
  const float* beta  = (const float*)d_in[5];
  const int*   ei    = (const int*)d_in[6];
  const int*   batch = (const int*)d_in[7];
  const int* esrc = ei;
  const int* edst = ei + EE;
  float* out = (float*)d_out;

  char* base = (char*)d_ws;
  size_t off = 0;
  auto alloc = [&](size_t b)->char*{
    char* p = base + off; off = (off + b + 255) & ~(size_t)255; return p;
  };
  uint32_t* Xbuf = (uint32_t*)alloc((size_t)MPAD * 256 * 2);  // bf16 row-major
  uint32_t* Xagg = (uint32_t*)alloc((size_t)MPAD * 256 * 2);
  uint32_t* Y    = (uint32_t*)alloc((size_t)MPAD * 256 * 2);  // bf16 pre-BN
  uint16_t* Wt0  = (uint16_t*)alloc(256 * 128 * 2);
  uint16_t* Wt1  = (uint16_t*)alloc(256 * 256 * 2);
  uint16_t* Wt2  = (uint16_t*)alloc(256 * 256 * 2);
  int*   degi   = (int*)  alloc((size_t)NN * 4);
  float* dis    = (float*)alloc((size_t)NN * 4);
  int*   rp     = (int*)  alloc((size_t)(NN + 1) * 4);
  int*   cursor = (int*)  alloc((size_t)NN * 4);
  int*   bsum   = (int*)  alloc(128 * 4);
  long long* cp = (long long*)alloc((size_t)EE * 8);
  float* pstat  = (float*)alloc((size_t)NBM * 2 * 256 * 4);
  float* ss     = (float*)alloc(512 * 4);
  int*   seg    = (int*)  alloc((BB + 1) * 4);
  float* pb     = (float*)alloc((size_t)BB * 8 * 512 * 4);

  hipMemsetAsync(degi, 0, (size_t)NN * 4, stream);
  k_deg<<<2048, 256, 0, stream>>>(edst, degi);
  k_scan1<<<98, 256, 0, stream>>>(degi, rp, bsum, dis);
  k_scan2<<<1, 1, 0, stream>>>(bsum, 98);
  k_scan3<<<98, 256, 0, stream>>>(rp, cursor, bsum);
  k_fill<<<2048, 256, 0, stream>>>(esrc, edst, dis, cursor, cp);
  k_sort<<<(NN + 255) / 256, 256, 0, stream>>>(rp, cp);
  k_wtall<<<640, 256, 0, stream>>>(W0, Wr, Wt0, Wt1, Wt2);
  k_cvtx<<<MPAD * 64 / 256, 256, 0, stream>>>(x, Xbuf);

  // layer 1 (K=128)
  k_agg128<<<MPAD / 16, 256, 0, stream>>>((const uint2*)Xbuf, rp, cp, dis, (uint2*)Xagg);
  k_gemm<128><<<dim3(NBM, 2), 512, 0, stream>>>((const uint16_t*)Xagg, Wt0, Y, pstat);
  k_finalize<<<1, 256, 0, stream>>>(pstat, gamma + 0, beta + 0, ss);
  k_bnapply<<<MPAD * 32 / 256, 256, 0, stream>>>((const uint4*)Y, ss, (uint4*)Xbuf);

  // layer 2 (K=256)
  k_agg256<<<MPAD / 16, 256, 0, stream>>>((const uint2*)Xbuf, rp, cp, dis, (uint2*)Xagg);
  k_gemm<256><<<dim3(NBM, 2), 512, 0, stream>>>((const uint16_t*)Xagg, Wt1, Y, pstat);
  k_finalize<<<1, 256, 0, stream>>>(pstat, gamma + 256, beta + 256, ss);
  k_bnapply<<<MPAD * 32 / 256, 256, 0, stream>>>((const uint4*)Y, ss, (uint4*)Xbuf);

  // layer 3 (K=256)
  k_agg256<<<MPAD / 16, 256, 0, stream>>>((const uint2*)Xbuf, rp, cp, dis, (uint2*)Xagg);
  k_gemm<256><<<dim3(NBM, 2), 512, 0, stream>>>((const uint16_t*)Xagg, Wt2, Y, pstat);
  k_finalize<<<1, 256, 0, stream>>>(pstat, gamma + 512, beta + 512, ss);
  k_bnapply<<<MPAD * 32 / 256, 256, 0, stream>>>((const uint4*)Y, ss, (uint4*)Xbuf);

  // pooling
  k_segstart<<<1, 128, 0, stream>>>(batch, seg);
  k_poolpart<<<dim3(BB, 8), 128, 0, stream>>>(Xbuf, seg, pb);
  k_poolred<<<BB, 256, 0, stream>>>(pb, seg, out);
}

// Round 8
// 868.812 us; speedup vs baseline: 1.0612x; 1.0612x over previous
//
#include <hip/hip_runtime.h>
#include <hip/hip_bf16.h>
#include <stdint.h>

// GCN: per layer  X_agg = (A_sym + D^-1) X ;  Y = X_agg @ W ; BN(gamma,beta) ; relu
// bias b cancels through BN -> skipped. agg-before-GEMM is exact-math equivalent.
// DETERMINISM (bitwise): CSR rows canonically sorted (wave bitonic k_sort) so the f32
// gather sums in a fixed order; BN stats via fixed-order shfl + per-block partials +
// fixed-order finalize (NO float atomics anywhere).
// agg256: 2-deep software pipeline (cp shfl-broadcast + double-buffered gathers).

#define NN 100000
#define EE 1600000
#define BB 64
#define MPAD 100096        // 391*256, zero-padded rows
#define NBM (MPAD / 256)   // 391 gemm row-blocks

typedef __attribute__((ext_vector_type(8))) short short8;
typedef __attribute__((ext_vector_type(4))) float f32x4;

__device__ __forceinline__ float bflo(uint32_t v){ return __uint_as_float(v << 16); }
__device__ __forceinline__ float bfhi(uint32_t v){ return __uint_as_float(v & 0xffff0000u); }
__device__ __forceinline__ uint32_t bfrne(float x){
  uint32_t u = __float_as_uint(x);
  return (u + 0x7fffu + ((u >> 16) & 1u)) >> 16;
}
__device__ __forceinline__ uint32_t bfpack(float a, float b){ return bfrne(a) | (bfrne(b) << 16); }
__device__ __forceinline__ float phi(long long p){
  return __uint_as_float((uint32_t)((unsigned long long)p >> 32));
}

__device__ __forceinline__ void gload_lds16(const void* g, void* l){
  __builtin_amdgcn_global_load_lds(
      (const __attribute__((address_space(1))) uint32_t*)g,
      (__attribute__((address_space(3))) uint32_t*)l, 16, 0, 0);
}

// ---------------- setup: degree, rsqrt, CSR ----------------
__global__ void k_deg(const int* __restrict__ dst, int* __restrict__ degi){
  for (int e = blockIdx.x * blockDim.x + threadIdx.x; e < EE; e += gridDim.x * blockDim.x)
    atomicAdd(&degi[dst[e]], 1);
}

__global__ void k_scan1(const int* __restrict__ degi, int* __restrict__ rp, int* __restrict__ bsum,
                        float* __restrict__ dis){
  __shared__ int lds[256];
  int b = blockIdx.x, t = threadIdx.x;
  int base = b * 1024 + t * 4;
  int v0 = (base + 0 < NN) ? degi[base + 0] : 0;
  int v1 = (base + 1 < NN) ? degi[base + 1] : 0;
  int v2 = (base + 2 < NN) ? degi[base + 2] : 0;
  int v3 = (base + 3 < NN) ? degi[base + 3] : 0;
  if (base + 0 < NN) dis[base + 0] = rsqrtf((float)v0 + 1.0f);
  if (base + 1 < NN) dis[base + 1] = rsqrtf((float)v1 + 1.0f);
  if (base + 2 < NN) dis[base + 2] = rsqrtf((float)v2 + 1.0f);
  if (base + 3 < NN) dis[base + 3] = rsqrtf((float)v3 + 1.0f);
  int s = v0 + v1 + v2 + v3;
  lds[t] = s; __syncthreads();
  for (int off = 1; off < 256; off <<= 1){
    int x = (t >= off) ? lds[t - off] : 0; __syncthreads();
    lds[t] += x; __syncthreads();
  }
  int excl = lds[t] - s;
  if (t == 255) bsum[b] = lds[255];
  if (base + 0 < NN) rp[base + 0] = excl;
  if (base + 1 < NN) rp[base + 1] = excl + v0;
  if (base + 2 < NN) rp[base + 2] = excl + v0 + v1;
  if (base + 3 < NN) rp[base + 3] = excl + v0 + v1 + v2;
}

__global__ void k_scan2(int* __restrict__ bsum, int nb){
  if (blockIdx.x == 0 && threadIdx.x == 0){
    int run = 0;
    for (int i = 0; i < nb; ++i){ int t = bsum[i]; bsum[i] = run; run += t; }
  }
}

__global__ void k_scan3(int* __restrict__ rp, int* __restrict__ cursor, const int* __restrict__ bsum){
  int b = blockIdx.x, t = threadIdx.x;
  int add = bsum[b];
  int base = b * 1024 + t * 4;
  #pragma unroll
  for (int j = 0; j < 4; ++j){
    int i = base + j;
    if (i < NN){ int v = rp[i] + add; rp[i] = v; cursor[i] = v; }
  }
  if (b == 0 && t == 0) rp[NN] = EE;
}

__global__ void k_fill(const int* __restrict__ src, const int* __restrict__ dst,
                       const float* __restrict__ dis, int* __restrict__ cursor,
                       long long* __restrict__ cp){
  for (int e = blockIdx.x * blockDim.x + threadIdx.x; e < EE; e += gridDim.x * blockDim.x){
    int s = src[e], d = dst[e];
    int pos = atomicAdd(&cursor[d], 1);
    float nrm = dis[s] * dis[d];
    long long v = (long long)(unsigned int)s | ((long long)(unsigned int)__float_as_uint(nrm) << 32);
    cp[pos] = v;
  }
}

// canonical per-row order: one WAVE per row, register bitonic sort via shfl_xor.
// duplicate edges pack identical 64-bit values -> instability among equals harmless.
__global__ void k_sort(const int* __restrict__ rp, long long* __restrict__ cp){
  int wid = (blockIdx.x * blockDim.x + threadIdx.x) >> 6;
  int lane = threadIdx.x & 63;
  if (wid >= NN) return;
  int beg = rp[wid], end = rp[wid + 1];
  int d = end - beg;
  if (d <= 1) return;
  if (d <= 64){
    long long key = (lane < d) ? cp[beg + lane] : 0x7fffffffffffffffLL;
    #pragma unroll
    for (int k = 2; k <= 64; k <<= 1){
      #pragma unroll
      for (int j = k >> 1; j > 0; j >>= 1){
        long long other = __shfl_xor(key, j);
        bool up = ((lane & k) == 0);
        bool keepMin = (((lane & j) == 0) == up);
        bool take = keepMin ? (other < key) : (other > key);
        if (take) key = other;
      }
    }
    if (lane < d) cp[beg + lane] = key;
  } else if (lane == 0){
    // fallback (deg>64 essentially never occurs for this graph; correctness only)
    for (int i = beg + 1; i < end; ++i){
      long long k2 = cp[i];
      int j = i - 1;
      while (j >= beg && cp[j] > k2){ cp[j + 1] = cp[j]; --j; }
      cp[j + 1] = k2;
    }
  }
}

// ---------------- all weights -> bf16 transposed Wt[c][k] ----------------
__global__ void k_wtall(const float* __restrict__ W0, const float* __restrict__ Wr,
                        uint16_t* __restrict__ Wt0, uint16_t* __restrict__ Wt1,
                        uint16_t* __restrict__ Wt2){
  int i = blockIdx.x * 256 + threadIdx.x;
  if (i < 32768){
    int c = i >> 7, k = i & 127;
    Wt0[i] = (uint16_t)bfrne(W0[k * 256 + c]);
  } else if (i < 32768 + 131072){
    int j = i - 32768;
    int m = j >> 16, jj = j & 65535;
    int c = jj >> 8, k = jj & 255;
    uint16_t v = (uint16_t)bfrne(Wr[m * 65536 + k * 256 + c]);
    if (m == 0) Wt1[jj] = v; else Wt2[jj] = v;
  }
}

// ---------------- x (f32) -> bf16 row-major [MPAD][128], zero-pad rows ----------------
__global__ void k_cvtx(const float* __restrict__ x, uint32_t* __restrict__ Xb){
  int i = blockIdx.x * 256 + threadIdx.x;   // over MPAD*64
  if (i >= MPAD * 64) return;
  int row = i >> 6;
  uint32_t r = 0u;
  if (row < NN){
    int col = (i & 63) * 2;
    r = bfpack(x[row * 128 + col], x[row * 128 + col + 1]);
  }
  Xb[i] = r;
}

// ---------------- aggregation K=256: one wave per row, 2-deep pipelined gather ----------------
// cp pack shared per 8-lane group (lane&7) + shfl broadcast; gathers double-buffered so
// pack i+2's loads are in flight during pack i's FMAs. Consumption order == sorted order.
__global__ void k_agg256(const uint2* __restrict__ Xin, const int* __restrict__ rp,
                         const long long* __restrict__ cp, const float* __restrict__ dis,
                         uint2* __restrict__ Xout){
  const uint2* C2 = (const uint2*)cp;   // .x = src, .y = nrm bits
  int lane = threadIdx.x & 63;
  int slot = threadIdx.x >> 6;
  int g8 = lane & 56;                   // 8-lane group base
  int row0 = blockIdx.x * 16 + slot;
  for (int rr = 0; rr < 4; ++rr){
    int row = row0 + rr * 4;
    if (row >= NN){
      if (row < MPAD){ uint2 z = {0u, 0u}; Xout[(size_t)row * 64 + lane] = z; }
      continue;
    }
    int beg = rp[row], end = rp[row + 1];
    int nf = (end - beg) >> 3;
    float a0 = 0.f, a1 = 0.f, a2 = 0.f, a3 = 0.f;
    uint2 cA = {0u,0u}, cB = {0u,0u};
    uint2 vA[8], vB[8];

    if (nf > 0){
      cA = C2[beg + (lane & 7)];
      #pragma unroll
      for (int u = 0; u < 8; ++u){
        int su = __shfl((int)cA.x, g8 | u);
        vA[u] = Xin[(size_t)su * 64 + lane];
      }
    }
    if (nf > 1){
      cB = C2[beg + 8 + (lane & 7)];
      #pragma unroll
      for (int u = 0; u < 8; ++u){
        int su = __shfl((int)cB.x, g8 | u);
        vB[u] = Xin[(size_t)su * 64 + lane];
      }
    }

#define CONSUME(c, v) { \
    _Pragma("unroll") \
    for (int u = 0; u < 8; ++u){ \
      float w = __uint_as_float((uint32_t)__shfl((int)c.y, g8 | u)); \
      a0 += w * bflo(v[u].x); a1 += w * bfhi(v[u].x); \
      a2 += w * bflo(v[u].y); a3 += w * bfhi(v[u].y); \
    } }
#define REFILL(c, v, pk) if ((pk) < nf){ \
    c = C2[beg + (pk) * 8 + (lane & 7)]; \
    _Pragma("unroll") \
    for (int u = 0; u < 8; ++u){ \
      int su = __shfl((int)c.x, g8 | u); \
      v[u] = Xin[(size_t)su * 64 + lane]; \
    } }

    int it = 0;
    while (it + 1 < nf){
      CONSUME(cA, vA); REFILL(cA, vA, it + 2);
      CONSUME(cB, vB); REFILL(cB, vB, it + 3);
      it += 2;
    }
    if (it < nf){ CONSUME(cA, vA); ++it; }
#undef CONSUME
#undef REFILL

    // tail (uniform across lanes -> broadcast loads)
    for (int e = beg + nf * 8; e < end; ++e){
      long long p0 = cp[e];
      float w = phi(p0);
      uint2 v = Xin[(size_t)(int)p0 * 64 + lane];
      a0 += w * bflo(v.x); a1 += w * bfhi(v.x);
      a2 += w * bflo(v.y); a3 += w * bfhi(v.y);
    }
    float dv = dis[row]; float sn = dv * dv;
    uint2 vs = Xin[(size_t)row * 64 + lane];
    a0 += sn * bflo(vs.x); a1 += sn * bfhi(vs.x);
    a2 += sn * bflo(vs.y); a3 += sn * bfhi(vs.y);
    uint2 o; o.x = bfpack(a0, a1); o.y = bfpack(a2, a3);
    Xout[(size_t)row * 64 + lane] = o;
  }
}

// ---------------- aggregation K=128: half-wave pair, uint2 per lane (unchanged) ----------------
__global__ void k_agg128(const uint2* __restrict__ Xin, const int* __restrict__ rp,
                         const long long* __restrict__ cp, const float* __restrict__ dis,
                         uint2* __restrict__ Xout){
  int lane = threadIdx.x & 63;
  int half = lane >> 5, j = lane & 31;
  int slot = threadIdx.x >> 6;
  int row0 = blockIdx.x * 16 + slot;
  for (int rr = 0; rr < 4; ++rr){
    int row = row0 + rr * 4;
    if (row >= NN){
      if (row < MPAD && half == 0){ uint2 z = {0u, 0u}; Xout[(size_t)row * 32 + j] = z; }
      continue;
    }
    int beg = rp[row], end = rp[row + 1];
    float a0 = 0.f, a1 = 0.f, a2 = 0.f, a3 = 0.f;
    int e = beg;
    for (; e + 8 <= end; e += 8){
      long long p[4]; uint2 v[4];
      #pragma unroll
      for (int u = 0; u < 4; ++u) p[u] = cp[e + u * 2 + half];
      #pragma unroll
      for (int u = 0; u < 4; ++u) v[u] = Xin[(size_t)(int)p[u] * 32 + j];
      #pragma unroll
      for (int u = 0; u < 4; ++u){
        float w = phi(p[u]);
        a0 += w * bflo(v[u].x); a1 += w * bfhi(v[u].x);
        a2 += w * bflo(v[u].y); a3 += w * bfhi(v[u].y);
      }
    }
    for (; e < end; e += 2){
      int idx = e + half;
      bool ok = idx < end;
      long long p0 = cp[ok ? idx : end - 1];
      float w = ok ? phi(p0) : 0.f;
      uint2 v = Xin[(size_t)(int)p0 * 32 + j];
      a0 += w * bflo(v.x); a1 += w * bfhi(v.x);
      a2 += w * bflo(v.y); a3 += w * bfhi(v.y);
    }
    a0 += __shfl_xor(a0, 32); a1 += __shfl_xor(a1, 32);
    a2 += __shfl_xor(a2, 32); a3 += __shfl_xor(a3, 32);
    if (half == 0){
      float dv = dis[row]; float sn = dv * dv;
      uint2 vs = Xin[(size_t)row * 32 + j];
      a0 += sn * bflo(vs.x); a1 += sn * bfhi(vs.x);
      a2 += sn * bflo(vs.y); a3 += sn * bfhi(vs.y);
      uint2 o; o.x = bfpack(a0, a1); o.y = bfpack(a2, a3);
      Xout[(size_t)row * 32 + j] = o;
    }
  }
}

// ---------------- GEMM: Y[MPAD][256](bf16) = A[MPAD][K] * Wt[256][K]^T, fused BN stats ----------------
template<int K>
__global__ __launch_bounds__(512) void k_gemm(const uint16_t* __restrict__ A,
                                              const uint16_t* __restrict__ Bt,
                                              uint32_t* __restrict__ Cb,
                                              float* __restrict__ pstat){
  __shared__ __align__(16) uint16_t lA[2][8192];   // chunk c = k8*256 + r
  __shared__ __align__(16) uint16_t lB[2][4096];   // chunk c = k8*128 + r
  __shared__ float lp[8][128];                      // [wave][64 colsum | 64 colsumsq]
  int tid = threadIdx.x;
  int l = tid & 63;
  int bm = blockIdx.x, bn = blockIdx.y;

  f32x4 acc[4][4];
  #pragma unroll
  for (int m = 0; m < 4; ++m)
    #pragma unroll
    for (int n = 0; n < 4; ++n){ f32x4 z = {0.f,0.f,0.f,0.f}; acc[m][n] = z; }

  int w = tid >> 6, wr = w >> 1, wc = w & 1;
  int rbase = wr * 64, cbase = wc * 64;
  int lrow = l & 15, lk8 = l >> 4;

  auto stage = [&](int kt, int buf){
    #pragma unroll
    for (int i = 0; i < 2; ++i){
      int c = i * 512 + tid;
      int k8 = c >> 8, r = c & 255;
      size_t ga = (size_t)(bm * 256 + r) * K + kt * 32 + k8 * 8;
      gload_lds16((const char*)(A + ga), (char*)&lA[buf][c * 8]);
    }
    int k8b = tid >> 7, rb = tid & 127;
    size_t gb = (size_t)(bn * 128 + rb) * K + kt * 32 + k8b * 8;
    gload_lds16((const char*)(Bt + gb), (char*)&lB[buf][tid * 8]);
  };

  stage(0, 0);
  __syncthreads();
  constexpr int NT = K / 32;
  for (int kt = 0; kt < NT; ++kt){
    int cur = kt & 1;
    if (kt + 1 < NT) stage(kt + 1, cur ^ 1);
    short8 afr[4], bfr[4];
    #pragma unroll
    for (int m = 0; m < 4; ++m)
      afr[m] = *(const short8*)&lA[cur][(lk8 * 256 + rbase + m * 16 + lrow) * 8];
    #pragma unroll
    for (int n = 0; n < 4; ++n)
      bfr[n] = *(const short8*)&lB[cur][(lk8 * 128 + cbase + n * 16 + lrow) * 8];
    #pragma unroll
    for (int m = 0; m < 4; ++m)
      #pragma unroll
      for (int n = 0; n < 4; ++n)
        acc[m][n] = __builtin_amdgcn_mfma_f32_16x16x32_bf16(afr[m], bfr[n], acc[m][n], 0, 0, 0);
    __syncthreads();
  }

  int grow0 = bm * 256 + rbase + (l >> 4) * 4;
  int gcol0 = bn * 128 + cbase + (l & 15);
  uint16_t* C16 = (uint16_t*)Cb;
  float sa[4] = {0.f,0.f,0.f,0.f}, sb[4] = {0.f,0.f,0.f,0.f};
  #pragma unroll
  for (int m = 0; m < 4; ++m){
    #pragma unroll
    for (int n = 0; n < 4; ++n){
      int col = gcol0 + n * 16;
      int r0 = grow0 + m * 16;
      f32x4 v = acc[m][n];
      #pragma unroll
      for (int q = 0; q < 4; ++q){
        C16[(size_t)(r0 + q) * 256 + col] = (uint16_t)bfrne(v[q]);
        sa[n] += v[q]; sb[n] += v[q] * v[q];
      }
    }
  }
  #pragma unroll
  for (int n = 0; n < 4; ++n){
    sa[n] += __shfl_xor(sa[n], 16); sa[n] += __shfl_xor(sa[n], 32);
    sb[n] += __shfl_xor(sb[n], 16); sb[n] += __shfl_xor(sb[n], 32);
  }
  if (l < 16){
    #pragma unroll
    for (int n = 0; n < 4; ++n){
      lp[w][n * 16 + l] = sa[n];
      lp[w][64 + n * 16 + l] = sb[n];
    }
  }
  __syncthreads();
  if (tid < 256){
    int kind = tid >> 7, c = tid & 127;
    int wc2 = c >> 6, cc = c & 63;
    float v = lp[wc2][kind * 64 + cc] + lp[2 + wc2][kind * 64 + cc]
            + lp[4 + wc2][kind * 64 + cc] + lp[6 + wc2][kind * 64 + cc];
    pstat[(size_t)(bm * 2 + bn) * 256 + kind * 128 + c] = v;
  }
}

// finalize: fixed-order 8-lane-ILP sum of per-block partials (f64) -> scale/shift.
__global__ void k_finalize(const float* __restrict__ pstat, const float* __restrict__ gamma,
                           const float* __restrict__ beta, float* __restrict__ ss){
  int c = threadIdx.x;            // global column 0..255
  int bn = c >> 7, lc = c & 127;
  double s[8], s2[8];
  #pragma unroll
  for (int j = 0; j < 8; ++j){ s[j] = 0.; s2[j] = 0.; }
  int bm = 0;
  for (; bm + 8 <= NBM; bm += 8){
    #pragma unroll
    for (int j = 0; j < 8; ++j){
      const float* p = pstat + (size_t)((bm + j) * 2 + bn) * 256;
      s[j]  += (double)p[lc];
      s2[j] += (double)p[128 + lc];
    }
  }
  for (; bm < NBM; ++bm){
    const float* p = pstat + (size_t)(bm * 2 + bn) * 256;
    s[0]  += (double)p[lc];
    s2[0] += (double)p[128 + lc];
  }
  double S  = ((s[0]+s[1])+(s[2]+s[3]))  + ((s[4]+s[5])+(s[6]+s[7]));
  double S2 = ((s2[0]+s2[1])+(s2[2]+s2[3])) + ((s2[4]+s2[5])+(s2[6]+s2[7]));
  double mean = S / (double)NN;
  double var  = S2 / (double)NN - mean * mean;
  float rstd = rsqrtf((float)var + 1e-5f);
  float sc = gamma[c] * rstd;
  ss[c] = sc;
  ss[256 + c] = beta[c] - (float)mean * sc;
}

// ---------------- BN + relu on bf16 Y -> bf16 X row-major [MPAD][256] ----------------
__global__ void k_bnapply(const uint4* __restrict__ Y, const float* __restrict__ ss,
                          uint4* __restrict__ X){
  int i = blockIdx.x * 256 + threadIdx.x;    // over MPAD*32, 8 bf16 each
  if (i >= MPAD * 32) return;
  uint4 v = Y[i];
  int c0 = (i & 31) * 8;
  float r0 = fmaxf(bflo(v.x) * ss[c0 + 0] + ss[256 + c0 + 0], 0.f);
  float r1 = fmaxf(bfhi(v.x) * ss[c0 + 1] + ss[256 + c0 + 1], 0.f);
  float r2 = fmaxf(bflo(v.y) * ss[c0 + 2] + ss[256 + c0 + 2], 0.f);
  float r3 = fmaxf(bfhi(v.y) * ss[c0 + 3] + ss[256 + c0 + 3], 0.f);
  float r4 = fmaxf(bflo(v.z) * ss[c0 + 4] + ss[256 + c0 + 4], 0.f);
  float r5 = fmaxf(bfhi(v.z) * ss[c0 + 5] + ss[256 + c0 + 5], 0.f);
  float r6 = fmaxf(bflo(v.w) * ss[c0 + 6] + ss[256 + c0 + 6], 0.f);
  float r7 = fmaxf(bfhi(v.w) * ss[c0 + 7] + ss[256 + c0 + 7], 0.f);
  uint4 o;
  o.x = bfpack(r0, r1); o.y = bfpack(r2, r3);
  o.z = bfpack(r4, r5); o.w = bfpack(r6, r7);
  X[i] = o;
}

// ---------------- pooling (seg bounds via inline binary search) ----------------
__device__ __forceinline__ int segfind(const int* __restrict__ batch, int g){
  if (g <= 0) return 0;
  if (g >= BB) return NN;
  int lo = 0, hi = NN;
  while (lo < hi){ int mid = (lo + hi) >> 1; if (batch[mid] < g) lo = mid + 1; else hi = mid; }
  return lo;
}

__global__ void k_poolpart(const uint32_t* __restrict__ X, const int* __restrict__ batch,
                           float* __restrict__ pb){
  int g = blockIdx.x, c = blockIdx.y, t = threadIdx.x;   // 128 threads
  int s = segfind(batch, g), e = segfind(batch, g + 1);
  int len = e - s;
  int c0 = s + (int)(((long long)len * c) >> 3);
  int c1 = s + (int)(((long long)len * (c + 1)) >> 3);
  float sm0 = 0.f, sm1 = 0.f, mx0 = -1e30f, mx1 = -1e30f;
  #pragma unroll 4
  for (int r = c0; r < c1; ++r){
    uint32_t v = X[(size_t)r * 128 + t];
    float a = bflo(v), b2 = bfhi(v);
    sm0 += a; sm1 += b2;
    mx0 = fmaxf(mx0, a); mx1 = fmaxf(mx1, b2);
  }
  float* p = pb + (size_t)(g * 8 + c) * 512;
  p[2 * t] = sm0; p[2 * t + 1] = sm1;
  p[256 + 2 * t] = mx0; p[256 + 2 * t + 1] = mx1;
}

__global__ void k_poolred(const float* __restrict__ pb, const int* __restrict__ batch,
                          float* __restrict__ out){
  int g = blockIdx.x, cc = threadIdx.x;   // 256 threads
  float s = 0.f, m = -1e30f;
  #pragma unroll
  for (int c = 0; c < 8; ++c){
    const float* p = pb + (size_t)(g * 8 + c) * 512;
    s += p[cc];
    m = fmaxf(m, p[256 + cc]);
  }
  float inv = 1.0f / (float)(segfind(batch, g + 1) - segfind(batch, g));
  out[g * 512 + cc] = s * inv;
  out[g * 512 + 256 + cc] = m;
}

// ---------------- launch ----------------
extern "C" void kernel_launch(void* const* d_in, const int* in_sizes, int n_in,
                              void* d_out, int out_size, void* d_ws, size_t ws_size,
                              hipStream_t stream){
  const float* x     = (const float*)d_in[0];
  const float* W0    = (const float*)d_in[1];
  const float* Wr    = (const float*)d_in[2];
  const float* gamma = (const float*)d_in[4];
  const float* beta  = (const float*)d_in[5];
  const int*   ei    = (const int*)d_in[6];
  const int*   batch = (const int*)d_in[7];
  const int* esrc = ei;
  const int* edst = ei + EE;
  float* out = (float*)d_out;

  char* base = (char*)d_ws;
  size_t off = 0;
  auto alloc = [&](size_t b)->char*{
    char* p = base + off; off = (off + b + 255) & ~(size_t)255; return p;
  };
  uint32_t* Xbuf = (uint32_t*)alloc((size_t)MPAD * 256 * 2);  // bf16 row-major
  uint32_t* Xagg = (uint32_t*)alloc((size_t)MPAD * 256 * 2);
  uint32_t* Y    = (uint32_t*)alloc((size_t)MPAD * 256 * 2);  // bf16 pre-BN
  uint16_t* Wt0  = (uint16_t*)alloc(256 * 128 * 2);
  uint16_t* Wt1  = (uint16_t*)alloc(256 * 256 * 2);
  uint16_t* Wt2  = (uint16_t*)alloc(256 * 256 * 2);
  int*   degi   = (int*)  alloc((size_t)NN * 4);
  float* dis    = (float*)alloc((size_t)NN * 4);
  int*   rp     = (int*)  alloc((size_t)(NN + 1) * 4);
  int*   cursor = (int*)  alloc((size_t)NN * 4);
  int*   bsum   = (int*)  alloc(128 * 4);
  long long* cp = (long long*)alloc((size_t)EE * 8);
  float* pstat  = (float*)alloc((size_t)NBM * 2 * 256 * 4);
  float* ss     = (float*)alloc(512 * 4);
  float* pb     = (float*)alloc((size_t)BB * 8 * 512 * 4);

  hipMemsetAsync(degi, 0, (size_t)NN * 4, stream);
  k_deg<<<2048, 256, 0, stream>>>(edst, degi);
  k_scan1<<<98, 256, 0, stream>>>(degi, rp, bsum, dis);
  k_scan2<<<1, 1, 0, stream>>>(bsum, 98);
  k_scan3<<<98, 256, 0, stream>>>(rp, cursor, bsum);
  k_fill<<<2048, 256, 0, stream>>>(esrc, edst, dis, cursor, cp);
  k_sort<<<NN / 4, 256, 0, stream>>>(rp, cp);
  k_wtall<<<640, 256, 0, stream>>>(W0, Wr, Wt0, Wt1, Wt2);
  k_cvtx<<<MPAD * 64 / 256, 256, 0, stream>>>(x, Xbuf);

  // layer 1 (K=128)
  k_agg128<<<MPAD / 16, 256, 0, stream>>>((const uint2*)Xbuf, rp, cp, dis, (uint2*)Xagg);
  k_gemm<128><<<dim3(NBM, 2), 512, 0, stream>>>((const uint16_t*)Xagg, Wt0, Y, pstat);
  k_finalize<<<1, 256, 0, stream>>>(pstat, gamma + 0, beta + 0, ss);
  k_bnapply<<<MPAD * 32 / 256, 256, 0, stream>>>((const uint4*)Y, ss, (uint4*)Xbuf);

  // layer 2 (K=256)
  k_agg256<<<MPAD / 16, 256, 0, stream>>>((const uint2*)Xbuf, rp, cp, dis, (uint2*)Xagg);
  k_gemm<256><<<dim3(NBM, 2), 512, 0, stream>>>((const uint16_t*)Xagg, Wt1, Y, pstat);
  k_finalize<<<1, 256, 0, stream>>>(pstat, gamma + 256, beta + 256, ss);
  k_bnapply<<<MPAD * 32 / 256, 256, 0, stream>>>((const uint4*)Y, ss, (uint4*)Xbuf);

  // layer 3 (K=256)
  k_agg256<<<MPAD / 16, 256, 0, stream>>>((const uint2*)Xbuf, rp, cp, dis, (uint2*)Xagg);
  k_gemm<256><<<dim3(NBM, 2), 512, 0, stream>>>((const uint16_t*)Xagg, Wt2, Y, pstat);
  k_finalize<<<1, 256, 0, stream>>>(pstat, gamma + 512, beta + 512, ss);
  k_bnapply<<<MPAD * 32 / 256, 256, 0, stream>>>((const uint4*)Y, ss, (uint4*)Xbuf);

  // pooling
  k_poolpart<<<dim3(BB, 8), 128, 0, stream>>>(Xbuf, batch, pb);
  k_poolred<<<BB, 256, 0, stream>>>(pb, batch, out);
}

// Round 9
// 849.856 us; speedup vs baseline: 1.0848x; 1.0223x over previous
//
#include <hip/hip_runtime.h>
#include <hip/hip_bf16.h>
#include <stdint.h>

// GCN: per layer  X_agg = (A_sym + D^-1) X ;  Y = X_agg @ W ; BN(gamma,beta) ; relu
// bias b cancels through BN -> skipped. agg-before-GEMM is exact-math equivalent.
// DETERMINISM (bitwise): CSR rows canonically sorted (wave bitonic k_sort); BN stats
// via fixed-order shfl + per-block partials + fixed-order finalize (no float atomics).
// agg kernels: simple 8-deep gather (28 VGPR, ~73% occ — L3-service-bound, more
// in-flight doesn't help per R8 A/B); NT loads on edge stream, NT stores on output.
// Layer-3 BN is applied on the fly inside pooling (saves one full bnapply pass).

#define NN 100000
#define EE 1600000
#define BB 64
#define MPAD 100096        // 391*256, zero-padded rows
#define NBM (MPAD / 256)   // 391 gemm row-blocks

typedef __attribute__((ext_vector_type(8))) short short8;
typedef __attribute__((ext_vector_type(4))) float f32x4;

__device__ __forceinline__ float bflo(uint32_t v){ return __uint_as_float(v << 16); }
__device__ __forceinline__ float bfhi(uint32_t v){ return __uint_as_float(v & 0xffff0000u); }
__device__ __forceinline__ uint32_t bfrne(float x){
  uint32_t u = __float_as_uint(x);
  return (u + 0x7fffu + ((u >> 16) & 1u)) >> 16;
}
__device__ __forceinline__ uint32_t bfpack(float a, float b){ return bfrne(a) | (bfrne(b) << 16); }
__device__ __forceinline__ float phi(long long p){
  return __uint_as_float((uint32_t)((unsigned long long)p >> 32));
}

__device__ __forceinline__ void gload_lds16(const void* g, void* l){
  __builtin_amdgcn_global_load_lds(
      (const __attribute__((address_space(1))) uint32_t*)g,
      (__attribute__((address_space(3))) uint32_t*)l, 16, 0, 0);
}

// ---------------- setup: degree, rsqrt, CSR ----------------
__global__ void k_deg(const int* __restrict__ dst, int* __restrict__ degi){
  for (int e = blockIdx.x * blockDim.x + threadIdx.x; e < EE; e += gridDim.x * blockDim.x)
    atomicAdd(&degi[dst[e]], 1);
}

__global__ void k_scan1(const int* __restrict__ degi, int* __restrict__ rp, int* __restrict__ bsum,
                        float* __restrict__ dis){
  __shared__ int lds[256];
  int b = blockIdx.x, t = threadIdx.x;
  int base = b * 1024 + t * 4;
  int v0 = (base + 0 < NN) ? degi[base + 0] : 0;
  int v1 = (base + 1 < NN) ? degi[base + 1] : 0;
  int v2 = (base + 2 < NN) ? degi[base + 2] : 0;
  int v3 = (base + 3 < NN) ? degi[base + 3] : 0;
  if (base + 0 < NN) dis[base + 0] = rsqrtf((float)v0 + 1.0f);
  if (base + 1 < NN) dis[base + 1] = rsqrtf((float)v1 + 1.0f);
  if (base + 2 < NN) dis[base + 2] = rsqrtf((float)v2 + 1.0f);
  if (base + 3 < NN) dis[base + 3] = rsqrtf((float)v3 + 1.0f);
  int s = v0 + v1 + v2 + v3;
  lds[t] = s; __syncthreads();
  for (int off = 1; off < 256; off <<= 1){
    int x = (t >= off) ? lds[t - off] : 0; __syncthreads();
    lds[t] += x; __syncthreads();
  }
  int excl = lds[t] - s;
  if (t == 255) bsum[b] = lds[255];
  if (base + 0 < NN) rp[base + 0] = excl;
  if (base + 1 < NN) rp[base + 1] = excl + v0;
  if (base + 2 < NN) rp[base + 2] = excl + v0 + v1;
  if (base + 3 < NN) rp[base + 3] = excl + v0 + v1 + v2;
}

__global__ void k_scan2(int* __restrict__ bsum, int nb){
  if (blockIdx.x == 0 && threadIdx.x == 0){
    int run = 0;
    for (int i = 0; i < nb; ++i){ int t = bsum[i]; bsum[i] = run; run += t; }
  }
}

__global__ void k_scan3(int* __restrict__ rp, int* __restrict__ cursor, const int* __restrict__ bsum){
  int b = blockIdx.x, t = threadIdx.x;
  int add = bsum[b];
  int base = b * 1024 + t * 4;
  #pragma unroll
  for (int j = 0; j < 4; ++j){
    int i = base + j;
    if (i < NN){ int v = rp[i] + add; rp[i] = v; cursor[i] = v; }
  }
  if (b == 0 && t == 0) rp[NN] = EE;
}

__global__ void k_fill(const int* __restrict__ src, const int* __restrict__ dst,
                       const float* __restrict__ dis, int* __restrict__ cursor,
                       long long* __restrict__ cp){
  for (int e = blockIdx.x * blockDim.x + threadIdx.x; e < EE; e += gridDim.x * blockDim.x){
    int s = src[e], d = dst[e];
    int pos = atomicAdd(&cursor[d], 1);
    float nrm = dis[s] * dis[d];
    long long v = (long long)(unsigned int)s | ((long long)(unsigned int)__float_as_uint(nrm) << 32);
    cp[pos] = v;
  }
}

// canonical per-row order: one WAVE per row, register bitonic sort via shfl_xor.
__global__ void k_sort(const int* __restrict__ rp, long long* __restrict__ cp){
  int wid = (blockIdx.x * blockDim.x + threadIdx.x) >> 6;
  int lane = threadIdx.x & 63;
  if (wid >= NN) return;
  int beg = rp[wid], end = rp[wid + 1];
  int d = end - beg;
  if (d <= 1) return;
  if (d <= 64){
    long long key = (lane < d) ? cp[beg + lane] : 0x7fffffffffffffffLL;
    #pragma unroll
    for (int k = 2; k <= 64; k <<= 1){
      #pragma unroll
      for (int j = k >> 1; j > 0; j >>= 1){
        long long other = __shfl_xor(key, j);
        bool up = ((lane & k) == 0);
        bool keepMin = (((lane & j) == 0) == up);
        bool take = keepMin ? (other < key) : (other > key);
        if (take) key = other;
      }
    }
    if (lane < d) cp[beg + lane] = key;
  } else if (lane == 0){
    for (int i = beg + 1; i < end; ++i){
      long long k2 = cp[i];
      int j = i - 1;
      while (j >= beg && cp[j] > k2){ cp[j + 1] = cp[j]; --j; }
      cp[j + 1] = k2;
    }
  }
}

// ---------------- prep: weights -> bf16 Wt[c][k] ; x -> bf16 row-major [MPAD][128] ----------------
__global__ void k_prep(const float* __restrict__ W0, const float* __restrict__ Wr,
                       uint16_t* __restrict__ Wt0, uint16_t* __restrict__ Wt1,
                       uint16_t* __restrict__ Wt2,
                       const float* __restrict__ x, uint32_t* __restrict__ Xb){
  int b = blockIdx.x;
  if (b < 640){
    int i = b * 256 + threadIdx.x;
    if (i < 32768){
      int c = i >> 7, k = i & 127;
      Wt0[i] = (uint16_t)bfrne(W0[k * 256 + c]);
    } else if (i < 32768 + 131072){
      int j = i - 32768;
      int m = j >> 16, jj = j & 65535;
      int c = jj >> 8, k = jj & 255;
      uint16_t v = (uint16_t)bfrne(Wr[m * 65536 + k * 256 + c]);
      if (m == 0) Wt1[jj] = v; else Wt2[jj] = v;
    }
  } else {
    int i = (b - 640) * 256 + threadIdx.x;   // over MPAD*64
    if (i >= MPAD * 64) return;
    int row = i >> 6;
    uint32_t r = 0u;
    if (row < NN){
      int col = (i & 63) * 2;
      r = bfpack(x[row * 128 + col], x[row * 128 + col + 1]);
    }
    Xb[i] = r;
  }
}

// ---------------- aggregation K=256: one wave per row, uint2 per lane ----------------
__global__ void k_agg256(const uint2* __restrict__ Xin, const int* __restrict__ rp,
                         const long long* __restrict__ cp, const float* __restrict__ dis,
                         uint2* __restrict__ Xout){
  int lane = threadIdx.x & 63;
  int slot = threadIdx.x >> 6;
  int row0 = blockIdx.x * 16 + slot;
  for (int rr = 0; rr < 4; ++rr){
    int row = row0 + rr * 4;
    if (row >= NN){
      if (row < MPAD)
        __builtin_nontemporal_store(0ull, (unsigned long long*)&Xout[(size_t)row * 64 + lane]);
      continue;
    }
    int beg = rp[row], end = rp[row + 1];
    float a0 = 0.f, a1 = 0.f, a2 = 0.f, a3 = 0.f;
    int e = beg;
    for (; e + 8 <= end; e += 8){
      long long p[8]; uint2 v[8];
      #pragma unroll
      for (int u = 0; u < 8; ++u) p[u] = __builtin_nontemporal_load(&cp[e + u]);
      #pragma unroll
      for (int u = 0; u < 8; ++u) v[u] = Xin[(size_t)(int)p[u] * 64 + lane];
      #pragma unroll
      for (int u = 0; u < 8; ++u){
        float w = phi(p[u]);
        a0 += w * bflo(v[u].x); a1 += w * bfhi(v[u].x);
        a2 += w * bflo(v[u].y); a3 += w * bfhi(v[u].y);
      }
    }
    for (; e < end; ++e){
      long long p0 = __builtin_nontemporal_load(&cp[e]);
      float w = phi(p0);
      uint2 v = Xin[(size_t)(int)p0 * 64 + lane];
      a0 += w * bflo(v.x); a1 += w * bfhi(v.x);
      a2 += w * bflo(v.y); a3 += w * bfhi(v.y);
    }
    float dv = dis[row]; float sn = dv * dv;
    uint2 vs = Xin[(size_t)row * 64 + lane];
    a0 += sn * bflo(vs.x); a1 += sn * bfhi(vs.x);
    a2 += sn * bflo(vs.y); a3 += sn * bfhi(vs.y);
    unsigned long long o = (unsigned long long)bfpack(a0, a1)
                         | ((unsigned long long)bfpack(a2, a3) << 32);
    __builtin_nontemporal_store(o, (unsigned long long*)&Xout[(size_t)row * 64 + lane]);
  }
}

// ---------------- aggregation K=128: half-wave pair, uint2 per lane ----------------
__global__ void k_agg128(const uint2* __restrict__ Xin, const int* __restrict__ rp,
                         const long long* __restrict__ cp, const float* __restrict__ dis,
                         uint2* __restrict__ Xout){
  int lane = threadIdx.x & 63;
  int half = lane >> 5, j = lane & 31;
  int slot = threadIdx.x >> 6;
  int row0 = blockIdx.x * 16 + slot;
  for (int rr = 0; rr < 4; ++rr){
    int row = row0 + rr * 4;
    if (row >= NN){
      if (row < MPAD && half == 0)
        __builtin_nontemporal_store(0ull, (unsigned long long*)&Xout[(size_t)row * 32 + j]);
      continue;
    }
    int beg = rp[row], end = rp[row + 1];
    float a0 = 0.f, a1 = 0.f, a2 = 0.f, a3 = 0.f;
    int e = beg;
    for (; e + 8 <= end; e += 8){
      long long p[4]; uint2 v[4];
      #pragma unroll
      for (int u = 0; u < 4; ++u) p[u] = __builtin_nontemporal_load(&cp[e + u * 2 + half]);
      #pragma unroll
      for (int u = 0; u < 4; ++u) v[u] = Xin[(size_t)(int)p[u] * 32 + j];
      #pragma unroll
      for (int u = 0; u < 4; ++u){
        float w = phi(p[u]);
        a0 += w * bflo(v[u].x); a1 += w * bfhi(v[u].x);
        a2 += w * bflo(v[u].y); a3 += w * bfhi(v[u].y);
      }
    }
    for (; e < end; e += 2){
      int idx = e + half;
      bool ok = idx < end;
      long long p0 = cp[ok ? idx : end - 1];
      float w = ok ? phi(p0) : 0.f;
      uint2 v = Xin[(size_t)(int)p0 * 32 + j];
      a0 += w * bflo(v.x); a1 += w * bfhi(v.x);
      a2 += w * bflo(v.y); a3 += w * bfhi(v.y);
    }
    a0 += __shfl_xor(a0, 32); a1 += __shfl_xor(a1, 32);
    a2 += __shfl_xor(a2, 32); a3 += __shfl_xor(a3, 32);
    if (half == 0){
      float dv = dis[row]; float sn = dv * dv;
      uint2 vs = Xin[(size_t)row * 32 + j];
      a0 += sn * bflo(vs.x); a1 += sn * bfhi(vs.x);
      a2 += sn * bflo(vs.y); a3 += sn * bfhi(vs.y);
      unsigned long long o = (unsigned long long)bfpack(a0, a1)
                           | ((unsigned long long)bfpack(a2, a3) << 32);
      __builtin_nontemporal_store(o, (unsigned long long*)&Xout[(size_t)row * 32 + j]);
    }
  }
}

// ---------------- GEMM: Y[MPAD][256](bf16) = A[MPAD][K] * Wt[256][K]^T, fused BN stats ----------------
template<int K>
__global__ __launch_bounds__(512) void k_gemm(const uint16_t* __restrict__ A,
                                              const uint16_t* __restrict__ Bt,
                                              uint32_t* __restrict__ Cb,
                                              float* __restrict__ pstat){
  __shared__ __align__(16) uint16_t lA[2][8192];   // chunk c = k8*256 + r
  __shared__ __align__(16) uint16_t lB[2][4096];   // chunk c = k8*128 + r
  __shared__ float lp[8][128];                      // [wave][64 colsum | 64 colsumsq]
  int tid = threadIdx.x;
  int l = tid & 63;
  int bm = blockIdx.x, bn = blockIdx.y;

  f32x4 acc[4][4];
  #pragma unroll
  for (int m = 0; m < 4; ++m)
    #pragma unroll
    for (int n = 0; n < 4; ++n){ f32x4 z = {0.f,0.f,0.f,0.f}; acc[m][n] = z; }

  int w = tid >> 6, wr = w >> 1, wc = w & 1;
  int rbase = wr * 64, cbase = wc * 64;
  int lrow = l & 15, lk8 = l >> 4;

  auto stage = [&](int kt, int buf){
    #pragma unroll
    for (int i = 0; i < 2; ++i){
      int c = i * 512 + tid;
      int k8 = c >> 8, r = c & 255;
      size_t ga = (size_t)(bm * 256 + r) * K + kt * 32 + k8 * 8;
      gload_lds16((const char*)(A + ga), (char*)&lA[buf][c * 8]);
    }
    int k8b = tid >> 7, rb = tid & 127;
    size_t gb = (size_t)(bn * 128 + rb) * K + kt * 32 + k8b * 8;
    gload_lds16((const char*)(Bt + gb), (char*)&lB[buf][tid * 8]);
  };

  stage(0, 0);
  __syncthreads();
  constexpr int NT = K / 32;
  for (int kt = 0; kt < NT; ++kt){
    int cur = kt & 1;
    if (kt + 1 < NT) stage(kt + 1, cur ^ 1);
    short8 afr[4], bfr[4];
    #pragma unroll
    for (int m = 0; m < 4; ++m)
      afr[m] = *(const short8*)&lA[cur][(lk8 * 256 + rbase + m * 16 + lrow) * 8];
    #pragma unroll
    for (int n = 0; n < 4; ++n)
      bfr[n] = *(const short8*)&lB[cur][(lk8 * 128 + cbase + n * 16 + lrow) * 8];
    #pragma unroll
    for (int m = 0; m < 4; ++m)
      #pragma unroll
      for (int n = 0; n < 4; ++n)
        acc[m][n] = __builtin_amdgcn_mfma_f32_16x16x32_bf16(afr[m], bfr[n], acc[m][n], 0, 0, 0);
    __syncthreads();
  }

  int grow0 = bm * 256 + rbase + (l >> 4) * 4;
  int gcol0 = bn * 128 + cbase + (l & 15);
  uint16_t* C16 = (uint16_t*)Cb;
  float sa[4] = {0.f,0.f,0.f,0.f}, sb[4] = {0.f,0.f,0.f,0.f};
  #pragma unroll
  for (int m = 0; m < 4; ++m){
    #pragma unroll
    for (int n = 0; n < 4; ++n){
      int col = gcol0 + n * 16;
      int r0 = grow0 + m * 16;
      f32x4 v = acc[m][n];
      #pragma unroll
      for (int q = 0; q < 4; ++q){
        C16[(size_t)(r0 + q) * 256 + col] = (uint16_t)bfrne(v[q]);
        sa[n] += v[q]; sb[n] += v[q] * v[q];
      }
    }
  }
  #pragma unroll
  for (int n = 0; n < 4; ++n){
    sa[n] += __shfl_xor(sa[n], 16); sa[n] += __shfl_xor(sa[n], 32);
    sb[n] += __shfl_xor(sb[n], 16); sb[n] += __shfl_xor(sb[n], 32);
  }
  if (l < 16){
    #pragma unroll
    for (int n = 0; n < 4; ++n){
      lp[w][n * 16 + l] = sa[n];
      lp[w][64 + n * 16 + l] = sb[n];
    }
  }
  __syncthreads();
  if (tid < 256){
    int kind = tid >> 7, c = tid & 127;
    int wc2 = c >> 6, cc = c & 63;
    float v = lp[wc2][kind * 64 + cc] + lp[2 + wc2][kind * 64 + cc]
            + lp[4 + wc2][kind * 64 + cc] + lp[6 + wc2][kind * 64 + cc];
    pstat[(size_t)(bm * 2 + bn) * 256 + kind * 128 + c] = v;
  }
}

// finalize: fixed-order 8-way-ILP sum of per-block partials (f64) -> scale/shift.
__global__ void k_finalize(const float* __restrict__ pstat, const float* __restrict__ gamma,
                           const float* __restrict__ beta, float* __restrict__ ss){
  int c = threadIdx.x;            // global column 0..255
  int bn = c >> 7, lc = c & 127;
  double s[8], s2[8];
  #pragma unroll
  for (int j = 0; j < 8; ++j){ s[j] = 0.; s2[j] = 0.; }
  int bm = 0;
  for (; bm + 8 <= NBM; bm += 8){
    #pragma unroll
    for (int j = 0; j < 8; ++j){
      const float* p = pstat + (size_t)((bm + j) * 2 + bn) * 256;
      s[j]  += (double)p[lc];
      s2[j] += (double)p[128 + lc];
    }
  }
  for (; bm < NBM; ++bm){
    const float* p = pstat + (size_t)(bm * 2 + bn) * 256;
    s[0]  += (double)p[lc];
    s2[0] += (double)p[128 + lc];
  }
  double S  = ((s[0]+s[1])+(s[2]+s[3]))  + ((s[4]+s[5])+(s[6]+s[7]));
  double S2 = ((s2[0]+s2[1])+(s2[2]+s2[3])) + ((s2[4]+s2[5])+(s2[6]+s2[7]));
  double mean = S / (double)NN;
  double var  = S2 / (double)NN - mean * mean;
  float rstd = rsqrtf((float)var + 1e-5f);
  float sc = gamma[c] * rstd;
  ss[c] = sc;
  ss[256 + c] = beta[c] - (float)mean * sc;
}

// ---------------- BN + relu on bf16 Y -> bf16 X row-major [MPAD][256] ----------------
__global__ void k_bnapply(const uint4* __restrict__ Y, const float* __restrict__ ss,
                          uint4* __restrict__ X){
  int i = blockIdx.x * 256 + threadIdx.x;    // over MPAD*32, 8 bf16 each
  if (i >= MPAD * 32) return;
  uint4 v = Y[i];
  int c0 = (i & 31) * 8;
  float r0 = fmaxf(bflo(v.x) * ss[c0 + 0] + ss[256 + c0 + 0], 0.f);
  float r1 = fmaxf(bfhi(v.x) * ss[c0 + 1] + ss[256 + c0 + 1], 0.f);
  float r2 = fmaxf(bflo(v.y) * ss[c0 + 2] + ss[256 + c0 + 2], 0.f);
  float r3 = fmaxf(bfhi(v.y) * ss[c0 + 3] + ss[256 + c0 + 3], 0.f);
  float r4 = fmaxf(bflo(v.z) * ss[c0 + 4] + ss[256 + c0 + 4], 0.f);
  float r5 = fmaxf(bfhi(v.z) * ss[c0 + 5] + ss[256 + c0 + 5], 0.f);
  float r6 = fmaxf(bflo(v.w) * ss[c0 + 6] + ss[256 + c0 + 6], 0.f);
  float r7 = fmaxf(bfhi(v.w) * ss[c0 + 7] + ss[256 + c0 + 7], 0.f);
  uint4 o;
  o.x = bfpack(r0, r1); o.y = bfpack(r2, r3);
  o.z = bfpack(r4, r5); o.w = bfpack(r6, r7);
  X[i] = o;
}

// ---------------- pooling: BN(ss) + relu applied on the fly from bf16 Y ----------------
__device__ __forceinline__ int segfind(const int* __restrict__ batch, int g){
  if (g <= 0) return 0;
  if (g >= BB) return NN;
  int lo = 0, hi = NN;
  while (lo < hi){ int mid = (lo + hi) >> 1; if (batch[mid] < g) lo = mid + 1; else hi = mid; }
  return lo;
}

__global__ void k_poolpart(const uint32_t* __restrict__ Y, const float* __restrict__ ss,
                           const int* __restrict__ batch, float* __restrict__ pb){
  int g = blockIdx.x, c = blockIdx.y, t = threadIdx.x;   // 128 threads, 2 cols each
  float sc0 = ss[2*t], sc1 = ss[2*t+1];
  float sh0 = ss[256+2*t], sh1 = ss[256+2*t+1];
  int s = segfind(batch, g), e = segfind(batch, g + 1);
  int len = e - s;
  int c0 = s + (int)(((long long)len * c) >> 3);
  int c1 = s + (int)(((long long)len * (c + 1)) >> 3);
  float sm0 = 0.f, sm1 = 0.f, mx0 = -1e30f, mx1 = -1e30f;
  #pragma unroll 4
  for (int r = c0; r < c1; ++r){
    uint32_t v = Y[(size_t)r * 128 + t];
    float a  = fmaxf(bflo(v) * sc0 + sh0, 0.f);
    float b2 = fmaxf(bfhi(v) * sc1 + sh1, 0.f);
    sm0 += a; sm1 += b2;
    mx0 = fmaxf(mx0, a); mx1 = fmaxf(mx1, b2);
  }
  float* p = pb + (size_t)(g * 8 + c) * 512;
  p[2 * t] = sm0; p[2 * t + 1] = sm1;
  p[256 + 2 * t] = mx0; p[256 + 2 * t + 1] = mx1;
}

__global__ void k_poolred(const float* __restrict__ pb, const int* __restrict__ batch,
                          float* __restrict__ out){
  int g = blockIdx.x, cc = threadIdx.x;   // 256 threads
  float s = 0.f, m = -1e30f;
  #pragma unroll
  for (int c = 0; c < 8; ++c){
    const float* p = pb + (size_t)(g * 8 + c) * 512;
    s += p[cc];
    m = fmaxf(m, p[256 + cc]);
  }
  float inv = 1.0f / (float)(segfind(batch, g + 1) - segfind(batch, g));
  out[g * 512 + cc] = s * inv;
  out[g * 512 + 256 + cc] = m;
}

// ---------------- launch ----------------
extern "C" void kernel_launch(void* const* d_in, const int* in_sizes, int n_in,
                              void* d_out, int out_size, void* d_ws, size_t ws_size,
                              hipStream_t stream){
  const float* x     = (const float*)d_in[0];
  const float* W0    = (const float*)d_in[1];
  const float* Wr    = (const float*)d_in[2];
  const float* gamma = (const float*)d_in[4];
  const float* beta  = (const float*)d_in[5];
  const int*   ei    = (const int*)d_in[6];
  const int*   batch = (const int*)d_in[7];
  const int* esrc = ei;
  const int* edst = ei + EE;
  float* out = (float*)d_out;

  char* base = (char*)d_ws;
  size_t off = 0;
  auto alloc = [&](size_t b)->char*{
    char* p = base + off; off = (off + b + 255) & ~(size_t)255; return p;
  };
  uint32_t* Xbuf = (uint32_t*)alloc((size_t)MPAD * 256 * 2);  // bf16 row-major
  uint32_t* Xagg = (uint32_t*)alloc((size_t)MPAD * 256 * 2);
  uint32_t* Y    = (uint32_t*)alloc((size_t)MPAD * 256 * 2);  // bf16 pre-BN
  uint16_t* Wt0  = (uint16_t*)alloc(256 * 128 * 2);
  uint16_t* Wt1  = (uint16_t*)alloc(256 * 256 * 2);
  uint16_t* Wt2  = (uint16_t*)alloc(256 * 256 * 2);
  int*   degi   = (int*)  alloc((size_t)NN * 4);
  float* dis    = (float*)alloc((size_t)NN * 4);
  int*   rp     = (int*)  alloc((size_t)(NN + 1) * 4);
  int*   cursor = (int*)  alloc((size_t)NN * 4);
  int*   bsum   = (int*)  alloc(128 * 4);
  long long* cp = (long long*)alloc((size_t)EE * 8);
  float* pstat  = (float*)alloc((size_t)NBM * 2 * 256 * 4);
  float* ss     = (float*)alloc(512 * 4);
  float* pb     = (float*)alloc((size_t)BB * 8 * 512 * 4);

  hipMemsetAsync(degi, 0, (size_t)NN * 4, stream);
  k_deg<<<2048, 256, 0, stream>>>(edst, degi);
  k_scan1<<<98, 256, 0, stream>>>(degi, rp, bsum, dis);
  k_scan2<<<1, 1, 0, stream>>>(bsum, 98);
  k_scan3<<<98, 256, 0, stream>>>(rp, cursor, bsum);
  k_fill<<<2048, 256, 0, stream>>>(esrc, edst, dis, cursor, cp);
  k_sort<<<NN / 4, 256, 0, stream>>>(rp, cp);
  k_prep<<<640 + MPAD * 64 / 256, 256, 0, stream>>>(W0, Wr, Wt0, Wt1, Wt2, x, Xbuf);

  // layer 1 (K=128)
  k_agg128<<<MPAD / 16, 256, 0, stream>>>((const uint2*)Xbuf, rp, cp, dis, (uint2*)Xagg);
  k_gemm<128><<<dim3(NBM, 2), 512, 0, stream>>>((const uint16_t*)Xagg, Wt0, Y, pstat);
  k_finalize<<<1, 256, 0, stream>>>(pstat, gamma + 0, beta + 0, ss);
  k_bnapply<<<MPAD * 32 / 256, 256, 0, stream>>>((const uint4*)Y, ss, (uint4*)Xbuf);

  // layer 2 (K=256)
  k_agg256<<<MPAD / 16, 256, 0, stream>>>((const uint2*)Xbuf, rp, cp, dis, (uint2*)Xagg);
  k_gemm<256><<<dim3(NBM, 2), 512, 0, stream>>>((const uint16_t*)Xagg, Wt1, Y, pstat);
  k_finalize<<<1, 256, 0, stream>>>(pstat, gamma + 256, beta + 256, ss);
  k_bnapply<<<MPAD * 32 / 256, 256, 0, stream>>>((const uint4*)Y, ss, (uint4*)Xbuf);

  // layer 3 (K=256)
  k_agg256<<<MPAD / 16, 256, 0, stream>>>((const uint2*)Xbuf, rp, cp, dis, (uint2*)Xagg);
  k_gemm<256><<<dim3(NBM, 2), 512, 0, stream>>>((const uint16_t*)Xagg, Wt2, Y, pstat);
  k_finalize<<<1, 256, 0, stream>>>(pstat, gamma + 512, beta + 512, ss);

  // pooling (BN(ss) applied on the fly to Y)
  k_poolpart<<<dim3(BB, 8), 128, 0, stream>>>(Y, ss, batch, pb);
  k_poolred<<<BB, 256, 0, stream>>>(pb, batch, out);
}

// Round 10
// 772.482 us; speedup vs baseline: 1.1935x; 1.1002x over previous
//
#include <hip/hip_runtime.h>
#include <hip/hip_bf16.h>
#include <stdint.h>

// GCN: per layer  X_agg = (A_sym + D^-1) X ;  Y = X_agg @ W ; BN(gamma,beta) ; relu
// bias b cancels through BN -> skipped. agg-before-GEMM is exact-math equivalent.
// DETERMINISM (bitwise): CSR rows canonically sorted (wave bitonic k_sort); BN stats
// via fixed-order shfl + per-block partials + fixed-order finalize (no float atomics).
// BN+relu of layer L is FUSED into layer L+1's gather with the exact same f32 op chain
// (fma -> relu -> bf16 RNE round -> expand) the old bnapply pass used -> bitwise-identical
// output, two full 100MB passes removed. Pooling applies layer-3 BN on the fly (R9-proven).
// NT stores only on agg output; cp loads are plain (NT loads cost +21MB FETCH in R9).

#define NN 100000
#define EE 1600000
#define BB 64
#define MPAD 100096        // 391*256, zero-padded rows
#define NBM (MPAD / 256)   // 391 gemm row-blocks

typedef __attribute__((ext_vector_type(8))) short short8;
typedef __attribute__((ext_vector_type(4))) float f32x4;

__device__ __forceinline__ float bflo(uint32_t v){ return __uint_as_float(v << 16); }
__device__ __forceinline__ float bfhi(uint32_t v){ return __uint_as_float(v & 0xffff0000u); }
__device__ __forceinline__ uint32_t bfrne(float x){
  uint32_t u = __float_as_uint(x);
  return (u + 0x7fffu + ((u >> 16) & 1u)) >> 16;
}
__device__ __forceinline__ uint32_t bfpack(float a, float b){ return bfrne(a) | (bfrne(b) << 16); }
__device__ __forceinline__ float phi(long long p){
  return __uint_as_float((uint32_t)((unsigned long long)p >> 32));
}
// BN+relu+bf16-round+expand: bitwise-identical to (bnapply-store-bf16 ; gather-reload)
__device__ __forceinline__ float bnr(float y, float sc, float sh){
  float t = fmaxf(y * sc + sh, 0.f);
  return __uint_as_float(bfrne(t) << 16);
}

__device__ __forceinline__ void gload_lds16(const void* g, void* l){
  __builtin_amdgcn_global_load_lds(
      (const __attribute__((address_space(1))) uint32_t*)g,
      (__attribute__((address_space(3))) uint32_t*)l, 16, 0, 0);
}

// ---------------- setup: degree, rsqrt, CSR ----------------
__global__ void k_deg(const int* __restrict__ dst, int* __restrict__ degi){
  for (int e = blockIdx.x * blockDim.x + threadIdx.x; e < EE; e += gridDim.x * blockDim.x)
    atomicAdd(&degi[dst[e]], 1);
}

__global__ void k_scan1(const int* __restrict__ degi, int* __restrict__ rp, int* __restrict__ bsum,
                        float* __restrict__ dis){
  __shared__ int lds[256];
  int b = blockIdx.x, t = threadIdx.x;
  int base = b * 1024 + t * 4;
  int v0 = (base + 0 < NN) ? degi[base + 0] : 0;
  int v1 = (base + 1 < NN) ? degi[base + 1] : 0;
  int v2 = (base + 2 < NN) ? degi[base + 2] : 0;
  int v3 = (base + 3 < NN) ? degi[base + 3] : 0;
  if (base + 0 < NN) dis[base + 0] = rsqrtf((float)v0 + 1.0f);
  if (base + 1 < NN) dis[base + 1] = rsqrtf((float)v1 + 1.0f);
  if (base + 2 < NN) dis[base + 2] = rsqrtf((float)v2 + 1.0f);
  if (base + 3 < NN) dis[base + 3] = rsqrtf((float)v3 + 1.0f);
  int s = v0 + v1 + v2 + v3;
  lds[t] = s; __syncthreads();
  for (int off = 1; off < 256; off <<= 1){
    int x = (t >= off) ? lds[t - off] : 0; __syncthreads();
    lds[t] += x; __syncthreads();
  }
  int excl = lds[t] - s;
  if (t == 255) bsum[b] = lds[255];
  if (base + 0 < NN) rp[base + 0] = excl;
  if (base + 1 < NN) rp[base + 1] = excl + v0;
  if (base + 2 < NN) rp[base + 2] = excl + v0 + v1;
  if (base + 3 < NN) rp[base + 3] = excl + v0 + v1 + v2;
}

// scan3 with scan2 folded in: block-local reduction of bsum[0..b-1]
__global__ void k_scan3(int* __restrict__ rp, int* __restrict__ cursor, const int* __restrict__ bsum){
  __shared__ int red[256];
  int b = blockIdx.x, t = threadIdx.x;
  red[t] = (t < b && t < 98) ? bsum[t] : 0;
  __syncthreads();
  for (int off = 128; off > 0; off >>= 1){
    if (t < off) red[t] += red[t + off];
    __syncthreads();
  }
  int add = red[0];
  int base = b * 1024 + t * 4;
  #pragma unroll
  for (int j = 0; j < 4; ++j){
    int i = base + j;
    if (i < NN){ int v = rp[i] + add; rp[i] = v; cursor[i] = v; }
  }
  if (b == 0 && t == 0) rp[NN] = EE;
}

__global__ void k_fill(const int* __restrict__ src, const int* __restrict__ dst,
                       const float* __restrict__ dis, int* __restrict__ cursor,
                       long long* __restrict__ cp){
  for (int e = blockIdx.x * blockDim.x + threadIdx.x; e < EE; e += gridDim.x * blockDim.x){
    int s = src[e], d = dst[e];
    int pos = atomicAdd(&cursor[d], 1);
    float nrm = dis[s] * dis[d];
    long long v = (long long)(unsigned int)s | ((long long)(unsigned int)__float_as_uint(nrm) << 32);
    cp[pos] = v;
  }
}

// canonical per-row order: one WAVE per row, register bitonic sort via shfl_xor.
__global__ void k_sort(const int* __restrict__ rp, long long* __restrict__ cp){
  int wid = (blockIdx.x * blockDim.x + threadIdx.x) >> 6;
  int lane = threadIdx.x & 63;
  if (wid >= NN) return;
  int beg = rp[wid], end = rp[wid + 1];
  int d = end - beg;
  if (d <= 1) return;
  if (d <= 64){
    long long key = (lane < d) ? cp[beg + lane] : 0x7fffffffffffffffLL;
    #pragma unroll
    for (int k = 2; k <= 64; k <<= 1){
      #pragma unroll
      for (int j = k >> 1; j > 0; j >>= 1){
        long long other = __shfl_xor(key, j);
        bool up = ((lane & k) == 0);
        bool keepMin = (((lane & j) == 0) == up);
        bool take = keepMin ? (other < key) : (other > key);
        if (take) key = other;
      }
    }
    if (lane < d) cp[beg + lane] = key;
  } else if (lane == 0){
    for (int i = beg + 1; i < end; ++i){
      long long k2 = cp[i];
      int j = i - 1;
      while (j >= beg && cp[j] > k2){ cp[j + 1] = cp[j]; --j; }
      cp[j + 1] = k2;
    }
  }
}

// ---------------- prep: weights -> bf16 Wt[c][k] ; x -> bf16 row-major [MPAD][128] ----------------
__global__ void k_prep(const float* __restrict__ W0, const float* __restrict__ Wr,
                       uint16_t* __restrict__ Wt0, uint16_t* __restrict__ Wt1,
                       uint16_t* __restrict__ Wt2,
                       const float* __restrict__ x, uint32_t* __restrict__ Xb){
  int b = blockIdx.x;
  if (b < 640){
    int i = b * 256 + threadIdx.x;
    if (i < 32768){
      int c = i >> 7, k = i & 127;
      Wt0[i] = (uint16_t)bfrne(W0[k * 256 + c]);
    } else if (i < 32768 + 131072){
      int j = i - 32768;
      int m = j >> 16, jj = j & 65535;
      int c = jj >> 8, k = jj & 255;
      uint16_t v = (uint16_t)bfrne(Wr[m * 65536 + k * 256 + c]);
      if (m == 0) Wt1[jj] = v; else Wt2[jj] = v;
    }
  } else {
    int i = (b - 640) * 256 + threadIdx.x;   // over MPAD*64
    if (i >= MPAD * 64) return;
    int row = i >> 6;
    uint32_t r = 0u;
    if (row < NN){
      int col = (i & 63) * 2;
      r = bfpack(x[row * 128 + col], x[row * 128 + col + 1]);
    }
    Xb[i] = r;
  }
}

// ---------------- aggregation K=256 with fused BN+relu of the INPUT (bitwise == bnapply+gather) ----
__global__ void k_agg256(const uint2* __restrict__ Yin, const int* __restrict__ rp,
                         const long long* __restrict__ cp, const float* __restrict__ dis,
                         const float* __restrict__ ss, uint2* __restrict__ Xout){
  int lane = threadIdx.x & 63;
  int slot = threadIdx.x >> 6;
  // lane covers bf16 cols 4*lane .. 4*lane+3
  float sc0 = ss[lane*4+0], sc1 = ss[lane*4+1], sc2 = ss[lane*4+2], sc3 = ss[lane*4+3];
  float sh0 = ss[256+lane*4+0], sh1 = ss[256+lane*4+1], sh2 = ss[256+lane*4+2], sh3 = ss[256+lane*4+3];
  int row0 = blockIdx.x * 16 + slot;
  for (int rr = 0; rr < 4; ++rr){
    int row = row0 + rr * 4;
    if (row >= NN){
      if (row < MPAD)
        __builtin_nontemporal_store(0ull, (unsigned long long*)&Xout[(size_t)row * 64 + lane]);
      continue;
    }
    int beg = rp[row], end = rp[row + 1];
    float a0 = 0.f, a1 = 0.f, a2 = 0.f, a3 = 0.f;
    int e = beg;
    for (; e + 8 <= end; e += 8){
      long long p[8]; uint2 v[8];
      #pragma unroll
      for (int u = 0; u < 8; ++u) p[u] = cp[e + u];
      #pragma unroll
      for (int u = 0; u < 8; ++u) v[u] = Yin[(size_t)(int)p[u] * 64 + lane];
      #pragma unroll
      for (int u = 0; u < 8; ++u){
        float w = phi(p[u]);
        a0 += w * bnr(bflo(v[u].x), sc0, sh0);
        a1 += w * bnr(bfhi(v[u].x), sc1, sh1);
        a2 += w * bnr(bflo(v[u].y), sc2, sh2);
        a3 += w * bnr(bfhi(v[u].y), sc3, sh3);
      }
    }
    for (; e < end; ++e){
      long long p0 = cp[e];
      float w = phi(p0);
      uint2 v = Yin[(size_t)(int)p0 * 64 + lane];
      a0 += w * bnr(bflo(v.x), sc0, sh0);
      a1 += w * bnr(bfhi(v.x), sc1, sh1);
      a2 += w * bnr(bflo(v.y), sc2, sh2);
      a3 += w * bnr(bfhi(v.y), sc3, sh3);
    }
    float dv = dis[row]; float sn = dv * dv;
    uint2 vs = Yin[(size_t)row * 64 + lane];
    a0 += sn * bnr(bflo(vs.x), sc0, sh0);
    a1 += sn * bnr(bfhi(vs.x), sc1, sh1);
    a2 += sn * bnr(bflo(vs.y), sc2, sh2);
    a3 += sn * bnr(bfhi(vs.y), sc3, sh3);
    unsigned long long o = (unsigned long long)bfpack(a0, a1)
                         | ((unsigned long long)bfpack(a2, a3) << 32);
    __builtin_nontemporal_store(o, (unsigned long long*)&Xout[(size_t)row * 64 + lane]);
  }
}

// ---------------- aggregation K=128 (layer 1, raw bf16 x input): half-wave pair ----------------
__global__ void k_agg128(const uint2* __restrict__ Xin, const int* __restrict__ rp,
                         const long long* __restrict__ cp, const float* __restrict__ dis,
                         uint2* __restrict__ Xout){
  int lane = threadIdx.x & 63;
  int half = lane >> 5, j = lane & 31;
  int slot = threadIdx.x >> 6;
  int row0 = blockIdx.x * 16 + slot;
  for (int rr = 0; rr < 4; ++rr){
    int row = row0 + rr * 4;
    if (row >= NN){
      if (row < MPAD && half == 0)
        __builtin_nontemporal_store(0ull, (unsigned long long*)&Xout[(size_t)row * 32 + j]);
      continue;
    }
    int beg = rp[row], end = rp[row + 1];
    float a0 = 0.f, a1 = 0.f, a2 = 0.f, a3 = 0.f;
    int e = beg;
    for (; e + 8 <= end; e += 8){
      long long p[4]; uint2 v[4];
      #pragma unroll
      for (int u = 0; u < 4; ++u) p[u] = cp[e + u * 2 + half];
      #pragma unroll
      for (int u = 0; u < 4; ++u) v[u] = Xin[(size_t)(int)p[u] * 32 + j];
      #pragma unroll
      for (int u = 0; u < 4; ++u){
        float w = phi(p[u]);
        a0 += w * bflo(v[u].x); a1 += w * bfhi(v[u].x);
        a2 += w * bflo(v[u].y); a3 += w * bfhi(v[u].y);
      }
    }
    for (; e < end; e += 2){
      int idx = e + half;
      bool ok = idx < end;
      long long p0 = cp[ok ? idx : end - 1];
      float w = ok ? phi(p0) : 0.f;
      uint2 v = Xin[(size_t)(int)p0 * 32 + j];
      a0 += w * bflo(v.x); a1 += w * bfhi(v.x);
      a2 += w * bflo(v.y); a3 += w * bfhi(v.y);
    }
    a0 += __shfl_xor(a0, 32); a1 += __shfl_xor(a1, 32);
    a2 += __shfl_xor(a2, 32); a3 += __shfl_xor(a3, 32);
    if (half == 0){
      float dv = dis[row]; float sn = dv * dv;
      uint2 vs = Xin[(size_t)row * 32 + j];
      a0 += sn * bflo(vs.x); a1 += sn * bfhi(vs.x);
      a2 += sn * bflo(vs.y); a3 += sn * bfhi(vs.y);
      unsigned long long o = (unsigned long long)bfpack(a0, a1)
                           | ((unsigned long long)bfpack(a2, a3) << 32);
      __builtin_nontemporal_store(o, (unsigned long long*)&Xout[(size_t)row * 32 + j]);
    }
  }
}

// ---------------- GEMM: Y[MPAD][256](bf16) = A[MPAD][K] * Wt[256][K]^T, fused BN stats ----------------
template<int K>
__global__ __launch_bounds__(512) void k_gemm(const uint16_t* __restrict__ A,
                                              const uint16_t* __restrict__ Bt,
                                              uint32_t* __restrict__ Cb,
                                              float* __restrict__ pstat){
  __shared__ __align__(16) uint16_t lA[2][8192];   // chunk c = k8*256 + r
  __shared__ __align__(16) uint16_t lB[2][4096];   // chunk c = k8*128 + r
  __shared__ float lp[8][128];                      // [wave][64 colsum | 64 colsumsq]
  int tid = threadIdx.x;
  int l = tid & 63;
  int bm = blockIdx.x, bn = blockIdx.y;

  f32x4 acc[4][4];
  #pragma unroll
  for (int m = 0; m < 4; ++m)
    #pragma unroll
    for (int n = 0; n < 4; ++n){ f32x4 z = {0.f,0.f,0.f,0.f}; acc[m][n] = z; }

  int w = tid >> 6, wr = w >> 1, wc = w & 1;
  int rbase = wr * 64, cbase = wc * 64;
  int lrow = l & 15, lk8 = l >> 4;

  auto stage = [&](int kt, int buf){
    #pragma unroll
    for (int i = 0; i < 2; ++i){
      int c = i * 512 + tid;
      int k8 = c >> 8, r = c & 255;
      size_t ga = (size_t)(bm * 256 + r) * K + kt * 32 + k8 * 8;
      gload_lds16((const char*)(A + ga), (char*)&lA[buf][c * 8]);
    }
    int k8b = tid >> 7, rb = tid & 127;
    size_t gb = (size_t)(bn * 128 + rb) * K + kt * 32 + k8b * 8;
    gload_lds16((const char*)(Bt + gb), (char*)&lB[buf][tid * 8]);
  };

  stage(0, 0);
  __syncthreads();
  constexpr int NT = K / 32;
  for (int kt = 0; kt < NT; ++kt){
    int cur = kt & 1;
    if (kt + 1 < NT) stage(kt + 1, cur ^ 1);
    short8 afr[4], bfr[4];
    #pragma unroll
    for (int m = 0; m < 4; ++m)
      afr[m] = *(const short8*)&lA[cur][(lk8 * 256 + rbase + m * 16 + lrow) * 8];
    #pragma unroll
    for (int n = 0; n < 4; ++n)
      bfr[n] = *(const short8*)&lB[cur][(lk8 * 128 + cbase + n * 16 + lrow) * 8];
    #pragma unroll
    for (int m = 0; m < 4; ++m)
      #pragma unroll
      for (int n = 0; n < 4; ++n)
        acc[m][n] = __builtin_amdgcn_mfma_f32_16x16x32_bf16(afr[m], bfr[n], acc[m][n], 0, 0, 0);
    __syncthreads();
  }

  int grow0 = bm * 256 + rbase + (l >> 4) * 4;
  int gcol0 = bn * 128 + cbase + (l & 15);
  uint16_t* C16 = (uint16_t*)Cb;
  float sa[4] = {0.f,0.f,0.f,0.f}, sb[4] = {0.f,0.f,0.f,0.f};
  #pragma unroll
  for (int m = 0; m < 4; ++m){
    #pragma unroll
    for (int n = 0; n < 4; ++n){
      int col = gcol0 + n * 16;
      int r0 = grow0 + m * 16;
      f32x4 v = acc[m][n];
      #pragma unroll
      for (int q = 0; q < 4; ++q){
        C16[(size_t)(r0 + q) * 256 + col] = (uint16_t)bfrne(v[q]);
        sa[n] += v[q]; sb[n] += v[q] * v[q];
      }
    }
  }
  #pragma unroll
  for (int n = 0; n < 4; ++n){
    sa[n] += __shfl_xor(sa[n], 16); sa[n] += __shfl_xor(sa[n], 32);
    sb[n] += __shfl_xor(sb[n], 16); sb[n] += __shfl_xor(sb[n], 32);
  }
  if (l < 16){
    #pragma unroll
    for (int n = 0; n < 4; ++n){
      lp[w][n * 16 + l] = sa[n];
      lp[w][64 + n * 16 + l] = sb[n];
    }
  }
  __syncthreads();
  if (tid < 256){
    int kind = tid >> 7, c = tid & 127;
    int wc2 = c >> 6, cc = c & 63;
    float v = lp[wc2][kind * 64 + cc] + lp[2 + wc2][kind * 64 + cc]
            + lp[4 + wc2][kind * 64 + cc] + lp[6 + wc2][kind * 64 + cc];
    pstat[(size_t)(bm * 2 + bn) * 256 + kind * 128 + c] = v;
  }
}

// finalize: fixed-order 8-way-ILP sum of per-block partials (f64) -> scale/shift.
__global__ void k_finalize(const float* __restrict__ pstat, const float* __restrict__ gamma,
                           const float* __restrict__ beta, float* __restrict__ ss){
  int c = threadIdx.x;            // global column 0..255
  int bn = c >> 7, lc = c & 127;
  double s[8], s2[8];
  #pragma unroll
  for (int j = 0; j < 8; ++j){ s[j] = 0.; s2[j] = 0.; }
  int bm = 0;
  for (; bm + 8 <= NBM; bm += 8){
    #pragma unroll
    for (int j = 0; j < 8; ++j){
      const float* p = pstat + (size_t)((bm + j) * 2 + bn) * 256;
      s[j]  += (double)p[lc];
      s2[j] += (double)p[128 + lc];
    }
  }
  for (; bm < NBM; ++bm){
    const float* p = pstat + (size_t)(bm * 2 + bn) * 256;
    s[0]  += (double)p[lc];
    s2[0] += (double)p[128 + lc];
  }
  double S  = ((s[0]+s[1])+(s[2]+s[3]))  + ((s[4]+s[5])+(s[6]+s[7]));
  double S2 = ((s2[0]+s2[1])+(s2[2]+s2[3])) + ((s2[4]+s2[5])+(s2[6]+s2[7]));
  double mean = S / (double)NN;
  double var  = S2 / (double)NN - mean * mean;
  float rstd = rsqrtf((float)var + 1e-5f);
  float sc = gamma[c] * rstd;
  ss[c] = sc;
  ss[256 + c] = beta[c] - (float)mean * sc;
}

// ---------------- pooling: BN(ss) + relu applied on the fly from bf16 Y ----------------
__device__ __forceinline__ int segfind(const int* __restrict__ batch, int g){
  if (g <= 0) return 0;
  if (g >= BB) return NN;
  int lo = 0, hi = NN;
  while (lo < hi){ int mid = (lo + hi) >> 1; if (batch[mid] < g) lo = mid + 1; else hi = mid; }
  return lo;
}

__global__ void k_poolpart(const uint32_t* __restrict__ Y, const float* __restrict__ ss,
                           const int* __restrict__ batch, float* __restrict__ pb){
  int g = blockIdx.x, c = blockIdx.y, t = threadIdx.x;   // 128 threads, 2 cols each
  float sc0 = ss[2*t], sc1 = ss[2*t+1];
  float sh0 = ss[256+2*t], sh1 = ss[256+2*t+1];
  int s = segfind(batch, g), e = segfind(batch, g + 1);
  int len = e - s;
  int c0 = s + (int)(((long long)len * c) >> 3);
  int c1 = s + (int)(((long long)len * (c + 1)) >> 3);
  float sm0 = 0.f, sm1 = 0.f, mx0 = -1e30f, mx1 = -1e30f;
  #pragma unroll 4
  for (int r = c0; r < c1; ++r){
    uint32_t v = Y[(size_t)r * 128 + t];
    float a  = fmaxf(bflo(v) * sc0 + sh0, 0.f);
    float b2 = fmaxf(bfhi(v) * sc1 + sh1, 0.f);
    sm0 += a; sm1 += b2;
    mx0 = fmaxf(mx0, a); mx1 = fmaxf(mx1, b2);
  }
  float* p = pb + (size_t)(g * 8 + c) * 512;
  p[2 * t] = sm0; p[2 * t + 1] = sm1;
  p[256 + 2 * t] = mx0; p[256 + 2 * t + 1] = mx1;
}

__global__ void k_poolred(const float* __restrict__ pb, const int* __restrict__ batch,
                          float* __restrict__ out){
  int g = blockIdx.x, cc = threadIdx.x;   // 256 threads
  float s = 0.f, m = -1e30f;
  #pragma unroll
  for (int c = 0; c < 8; ++c){
    const float* p = pb + (size_t)(g * 8 + c) * 512;
    s += p[cc];
    m = fmaxf(m, p[256 + cc]);
  }
  float inv = 1.0f / (float)(segfind(batch, g + 1) - segfind(batch, g));
  out[g * 512 + cc] = s * inv;
  out[g * 512 + 256 + cc] = m;
}

// ---------------- launch ----------------
extern "C" void kernel_launch(void* const* d_in, const int* in_sizes, int n_in,
                              void* d_out, int out_size, void* d_ws, size_t ws_size,
                              hipStream_t stream){
  const float* x     = (const float*)d_in[0];
  const float* W0    = (const float*)d_in[1];
  const float* Wr    = (const float*)d_in[2];
  const float* gamma = (const float*)d_in[4];
  const float* beta  = (const float*)d_in[5];
  const int*   ei    = (const int*)d_in[6];
  const int*   batch = (const int*)d_in[7];
  const int* esrc = ei;
  const int* edst = ei + EE;
  float* out = (float*)d_out;

  char* base = (char*)d_ws;
  size_t off = 0;
  auto alloc = [&](size_t b)->char*{
    char* p = base + off; off = (off + b + 255) & ~(size_t)255; return p;
  };
  uint32_t* Xbuf = (uint32_t*)alloc((size_t)MPAD * 128 * 2);  // bf16 [MPAD][128] (layer-1 input)
  uint32_t* Xagg = (uint32_t*)alloc((size_t)MPAD * 256 * 2);  // A-tile buffer
  uint32_t* Y1   = (uint32_t*)alloc((size_t)MPAD * 256 * 2);  // bf16 pre-BN
  uint32_t* Y2   = (uint32_t*)alloc((size_t)MPAD * 256 * 2);
  uint16_t* Wt0  = (uint16_t*)alloc(256 * 128 * 2);
  uint16_t* Wt1  = (uint16_t*)alloc(256 * 256 * 2);
  uint16_t* Wt2  = (uint16_t*)alloc(256 * 256 * 2);
  int*   degi   = (int*)  alloc((size_t)NN * 4);
  float* dis    = (float*)alloc((size_t)NN * 4);
  int*   rp     = (int*)  alloc((size_t)(NN + 1) * 4);
  int*   cursor = (int*)  alloc((size_t)NN * 4);
  int*   bsum   = (int*)  alloc(128 * 4);
  long long* cp = (long long*)alloc((size_t)EE * 8);
  float* pstat  = (float*)alloc((size_t)NBM * 2 * 256 * 4);
  float* ss     = (float*)alloc(512 * 4);
  float* pb     = (float*)alloc((size_t)BB * 8 * 512 * 4);

  hipMemsetAsync(degi, 0, (size_t)NN * 4, stream);
  k_deg<<<2048, 256, 0, stream>>>(edst, degi);
  k_scan1<<<98, 256, 0, stream>>>(degi, rp, bsum, dis);
  k_scan3<<<98, 256, 0, stream>>>(rp, cursor, bsum);
  k_fill<<<2048, 256, 0, stream>>>(esrc, edst, dis, cursor, cp);
  k_sort<<<NN / 4, 256, 0, stream>>>(rp, cp);
  k_prep<<<640 + MPAD * 64 / 256, 256, 0, stream>>>(W0, Wr, Wt0, Wt1, Wt2, x, Xbuf);

  // layer 1 (K=128, raw x input)
  k_agg128<<<MPAD / 16, 256, 0, stream>>>((const uint2*)Xbuf, rp, cp, dis, (uint2*)Xagg);
  k_gemm<128><<<dim3(NBM, 2), 512, 0, stream>>>((const uint16_t*)Xagg, Wt0, Y1, pstat);
  k_finalize<<<1, 256, 0, stream>>>(pstat, gamma + 0, beta + 0, ss);

  // layer 2 (K=256, BN(ss) fused into the gather of Y1)
  k_agg256<<<MPAD / 16, 256, 0, stream>>>((const uint2*)Y1, rp, cp, dis, ss, (uint2*)Xagg);
  k_gemm<256><<<dim3(NBM, 2), 512, 0, stream>>>((const uint16_t*)Xagg, Wt1, Y2, pstat);
  k_finalize<<<1, 256, 0, stream>>>(pstat, gamma + 256, beta + 256, ss);

  // layer 3 (K=256, BN(ss) fused into the gather of Y2)
  k_agg256<<<MPAD / 16, 256, 0, stream>>>((const uint2*)Y2, rp, cp, dis, ss, (uint2*)Xagg);
  k_gemm<256><<<dim3(NBM, 2), 512, 0, stream>>>((const uint16_t*)Xagg, Wt2, Y1, pstat);
  k_finalize<<<1, 256, 0, stream>>>(pstat, gamma + 512, beta + 512, ss);

  // pooling (BN(ss) applied on the fly to Y1)
  k_poolpart<<<dim3(BB, 8), 128, 0, stream>>>(Y1, ss, batch, pb);
  k_poolred<<<BB, 256, 0, stream>>>(pb, batch, out);
}